// Round 15
// baseline (93.035 us; speedup 1.0000x reference)
//
#include <hip/hip_runtime.h>
#include <math.h>

#define NN 4096        // nodes
#define DIM 256        // hidden
#define NHEAD 8
#define HDIM 32
#define DFF 512
#define CAP 128        // max nonzeros per row (mean ~41, max ~75 at p=.01)
#define EPS_BN 1e-5f
#define QSCALE 0.0625f // D^-0.5
#define MB (1u << 20)

typedef __attribute__((ext_vector_type(8))) short short8;
typedef __attribute__((ext_vector_type(4))) float f32x4;

__device__ inline ushort f2bf(float x) {   // RNE float->bf16
    unsigned u = __builtin_bit_cast(unsigned, x);
    unsigned r = u + 0x7FFF + ((u >> 16) & 1);
    return (ushort)(r >> 16);
}
__device__ inline float bf2f(ushort u) {
    return __builtin_bit_cast(float, (unsigned)u << 16);
}
__device__ inline float bflo(unsigned u) { return __builtin_bit_cast(float, u << 16); }
__device__ inline float bfhi(unsigned u) { return __builtin_bit_cast(float, u & 0xFFFF0000u); }

// ---------------- convert WEIGHTS fp32 -> bf16 (256 blocks) ----------------
__global__ __launch_bounds__(256) void convert_w(
    const float* __restrict__ Wq, const float* __restrict__ Wk,
    const float* __restrict__ Wv, const float* __restrict__ Wo,
    const float* __restrict__ W1, const float* __restrict__ W2,
    ushort* __restrict__ wqkv, ushort* __restrict__ wo_b,
    ushort* __restrict__ w1_b, ushort* __restrict__ w2_b)
{
    int b = blockIdx.x, tid = threadIdx.x;
    if (b >= 96 && b < 128) {
        // Wo permuted convert: dest[row][h*32+d] = src[row][d*8+h]
        int off = b - 96;
        int row = off * 8 + (tid >> 5), t = tid & 31;
        int hh = t >> 2, dd0 = (t & 3) * 8;
        const float* src = Wo + (size_t)row * 256 + hh;
        ushort tmp[8];
        #pragma unroll
        for (int i = 0; i < 8; ++i) tmp[i] = f2bf(src[(size_t)(dd0 + i) * 8]);
        uint4 u;
        u.x = (unsigned)tmp[0] | ((unsigned)tmp[1] << 16);
        u.y = (unsigned)tmp[2] | ((unsigned)tmp[3] << 16);
        u.z = (unsigned)tmp[4] | ((unsigned)tmp[5] << 16);
        u.w = (unsigned)tmp[6] | ((unsigned)tmp[7] << 16);
        *(uint4*)(wo_b + (size_t)row * 256 + hh * 32 + dd0) = u;
        return;
    }
    const float* s; ushort* d; int off;
    if      (b < 32)  { s = Wq; d = wqkv;          off = b; }
    else if (b < 64)  { s = Wk; d = wqkv + 65536;  off = b - 32; }
    else if (b < 96)  { s = Wv; d = wqkv + 131072; off = b - 64; }
    else if (b < 192) { s = W1; d = w1_b;          off = b - 128; }
    else              { s = W2; d = w2_b;          off = b - 192; }
    size_t base = (size_t)off * 2048 + (size_t)tid * 8;
    float4 f0 = *(const float4*)(s + base);
    float4 f1 = *(const float4*)(s + base + 4);
    uint4 u;
    u.x = (unsigned)f2bf(f0.x) | ((unsigned)f2bf(f0.y) << 16);
    u.y = (unsigned)f2bf(f0.z) | ((unsigned)f2bf(f0.w) << 16);
    u.z = (unsigned)f2bf(f1.x) | ((unsigned)f2bf(f1.y) << 16);
    u.w = (unsigned)f2bf(f1.z) | ((unsigned)f2bf(f1.w) << 16);
    *(uint4*)(d + base) = u;
}

// ---------------- fused: QKV gemm (blocks 0..767, fp32 h on-load) ----------
//                  + A nz-scan (768..4863). No fences, no atomics.
#define LDP 88
#define TSTRIDE 74
__global__ __launch_bounds__(256) void qkv_ascan(
    const float* __restrict__ hF, const ushort* __restrict__ B,
    ushort* __restrict__ qh, ushort* __restrict__ kvh,
    float* __restrict__ vpart,
    const float* __restrict__ Araw, unsigned* __restrict__ packed,
    int* __restrict__ cnt)
{
    __shared__ ushort As[64][LDP];
    __shared__ ushort Bs[64][LDP];
    __shared__ float sRedS[8][64];
    int b = blockIdx.x, tid = threadIdx.x;

    if (b >= 768) {
        // ---- A-scan branch ----
        int* scan = (int*)&As[0][0];
        int n = b - 768;
        const float* row = Araw + (size_t)n * NN;
        float4 vals[4];
        int c = 0;
        #pragma unroll
        for (int i = 0; i < 4; ++i) {
            vals[i] = *(const float4*)(row + i * 1024 + tid * 4);
            c += (vals[i].x != 0.f) + (vals[i].y != 0.f)
               + (vals[i].z != 0.f) + (vals[i].w != 0.f);
        }
        scan[tid] = c;
        __syncthreads();
        for (int off = 1; off < 256; off <<= 1) {
            int t = (tid >= off) ? scan[tid - off] : 0;
            __syncthreads();
            scan[tid] += t;
            __syncthreads();
        }
        int pos = scan[tid] - c;       // exclusive prefix
        int total = scan[255];
        #pragma unroll
        for (int i = 0; i < 4; ++i) {
            int cb = i * 1024 + tid * 4;
            float4 v = vals[i];
            if (v.x != 0.f && pos < CAP) { packed[n*CAP+pos] = ((unsigned)f2bf(v.x) << 16) | (unsigned)cb;       ++pos; }
            if (v.y != 0.f && pos < CAP) { packed[n*CAP+pos] = ((unsigned)f2bf(v.y) << 16) | (unsigned)(cb + 1); ++pos; }
            if (v.z != 0.f && pos < CAP) { packed[n*CAP+pos] = ((unsigned)f2bf(v.z) << 16) | (unsigned)(cb + 2); ++pos; }
            if (v.w != 0.f && pos < CAP) { packed[n*CAP+pos] = ((unsigned)f2bf(v.w) << 16) | (unsigned)(cb + 3); ++pos; }
        }
        if (tid == 0) cnt[n] = min(total, CAP);
        return;
    }

    // ---- QKV GEMM branch (A = fp32 h, RNE-converted on load) ----
    int lane = tid & 63, w = tid >> 6;
    int wm = (w >> 1) * 32, wn = (w & 1) * 32;
    int xcd = b & 7, pos = b >> 3;
    int by = xcd * 8 + pos / 12;
    int bx = pos % 12;
    int m0 = by * 64, n0 = bx * 64;
    int l15 = lane & 15, lk = lane >> 4;
    int srow = tid >> 3;
    int scol = (tid & 7) * 8;

    f32x4 acc[2][2] = {};
    for (int k0 = 0; k0 < DIM; k0 += 64) {
        const ushort* Bg = B + (size_t)(n0 + srow) * DIM + scol + k0;
        uint4 gb0 = *(const uint4*)Bg;
        uint4 gb1 = *(const uint4*)(Bg + (size_t)32 * DIM);
        const float* Af = hF + (size_t)(m0 + srow) * DIM + scol + k0;
        float4 a0 = *(const float4*)Af;
        float4 a1 = *(const float4*)(Af + 4);
        float4 c0 = *(const float4*)(Af + (size_t)32 * DIM);
        float4 c1 = *(const float4*)(Af + (size_t)32 * DIM + 4);
        uint4 ga0, ga1;
        ga0.x = (unsigned)f2bf(a0.x) | ((unsigned)f2bf(a0.y) << 16);
        ga0.y = (unsigned)f2bf(a0.z) | ((unsigned)f2bf(a0.w) << 16);
        ga0.z = (unsigned)f2bf(a1.x) | ((unsigned)f2bf(a1.y) << 16);
        ga0.w = (unsigned)f2bf(a1.z) | ((unsigned)f2bf(a1.w) << 16);
        ga1.x = (unsigned)f2bf(c0.x) | ((unsigned)f2bf(c0.y) << 16);
        ga1.y = (unsigned)f2bf(c0.z) | ((unsigned)f2bf(c0.w) << 16);
        ga1.z = (unsigned)f2bf(c1.x) | ((unsigned)f2bf(c1.y) << 16);
        ga1.w = (unsigned)f2bf(c1.z) | ((unsigned)f2bf(c1.w) << 16);
        __syncthreads();
        *(uint4*)&As[srow][scol]      = ga0;
        *(uint4*)&As[srow + 32][scol] = ga1;
        *(uint4*)&Bs[srow][scol]      = gb0;
        *(uint4*)&Bs[srow + 32][scol] = gb1;
        __syncthreads();
        #pragma unroll
        for (int ks = 0; ks < 2; ++ks) {
            int kc = ks * 32 + lk * 8;
            short8 a0s = *(const short8*)&As[wm      + l15][kc];
            short8 a1s = *(const short8*)&As[wm + 16 + l15][kc];
            short8 b0s = *(const short8*)&Bs[wn      + l15][kc];
            short8 b1s = *(const short8*)&Bs[wn + 16 + l15][kc];
            acc[0][0] = __builtin_amdgcn_mfma_f32_16x16x32_bf16(a0s, b0s, acc[0][0], 0, 0, 0);
            acc[0][1] = __builtin_amdgcn_mfma_f32_16x16x32_bf16(a0s, b1s, acc[0][1], 0, 0, 0);
            acc[1][0] = __builtin_amdgcn_mfma_f32_16x16x32_bf16(a1s, b0s, acc[1][0], 0, 0, 0);
            acc[1][1] = __builtin_amdgcn_mfma_f32_16x16x32_bf16(a1s, b1s, acc[1][1], 0, 0, 0);
        }
    }
    // transpose via LDS (reuse As), coalesced 16B chunk stores
    ushort* sT = &As[0][0];
    int seg = n0 >> 8, ddBase = (n0 & 255) >> 3;
    float sp[2] = {0.f, 0.f};
    __syncthreads();
    #pragma unroll
    for (int mt = 0; mt < 2; ++mt)
        #pragma unroll
        for (int nt = 0; nt < 2; ++nt) {
            int col_l = wn + nt * 16 + l15;
            #pragma unroll
            for (int i = 0; i < 4; ++i) {
                int row_l = wm + mt * 16 + lk * 4 + i;
                float v = acc[mt][nt][i];
                if (seg == 0) v *= QSCALE;
                sT[row_l * TSTRIDE + col_l] = f2bf(v);
                sp[nt] += v;
            }
        }
    __syncthreads();
    for (int c = tid; c < 512; c += 256) {
        int rl = c & 63, hh = c >> 6;
        const ushort* tp = sT + rl * TSTRIDE + hh;
        uint4 pk;
        pk.x = (unsigned)tp[0]  | ((unsigned)tp[8]  << 16);
        pk.y = (unsigned)tp[16] | ((unsigned)tp[24] << 16);
        pk.z = (unsigned)tp[32] | ((unsigned)tp[40] << 16);
        pk.w = (unsigned)tp[48] | ((unsigned)tp[56] << 16);
        int row = m0 + rl;
        if (seg == 0)
            *(uint4*)(qh + ((size_t)hh * NN + row) * HDIM + ddBase) = pk;
        else
            *(uint4*)(kvh + ((size_t)hh * NN + row) * 64 +
                      ((seg == 2) ? 32 : 0) + ddBase) = pk;
    }
    if (seg == 2) {
        int slot = ((wm >> 5) << 2) | lk;
        sRedS[slot][wn + l15]      = sp[0];
        sRedS[slot][wn + 16 + l15] = sp[1];
        __syncthreads();
        if (tid < 64) {
            float ss = 0.f;
            #pragma unroll
            for (int r = 0; r < 8; ++r) ss += sRedS[r][tid];
            vpart[(size_t)by * 256 + (n0 & 255) + tid] = ss;
        }
    }
}

// ---------------- vsum final: 64 coalesced partials -> vsumh[h][d] ---------
__global__ __launch_bounds__(256) void vsum_final(
    const float* __restrict__ vpart, float* __restrict__ vsumh)
{
    int c = threadIdx.x;
    float s = 0.f;
    #pragma unroll 8
    for (int b = 0; b < 64; ++b) s += vpart[(size_t)b * 256 + c];
    vsumh[(c & 7) * HDIM + (c >> 3)] = s;
}

// ---------------- bf16 MFMA GEMM (modes 0/1/2/3), XCD-swizzled -------------
// aMode 0: A bf16 [M,K]. aMode 1: A fp32 + on-load BN (scale/shift from LDS,
//   computed in prologue when bnfin=1). aMode 2: A bf16 head-major.
// storeMode 0: Cf fp32 (+resid). 1: Cb bf16 (relu opt).
//   3: Cf fp32, residual recomputed as yres*scR+shR (Cf may alias yres).
// bnstat: per-block col sum/sumsq partials -> bnps/bnpq [nby][256].
// bnfin: prologue reduces bnpsIn/bnpqIn + gIn/bshIn -> LDS scale/shift,
//   and redundantly writes scOut/shOut (identical bits from every block).
__global__ __launch_bounds__(256) void gemm_bf(
    const void* __restrict__ Aptr, const ushort* __restrict__ B,
    const float* __restrict__ resid,
    const float* yres, const float* __restrict__ scR, const float* __restrict__ shR,
    float* Cf, ushort* __restrict__ Cb,
    float* __restrict__ bnps, float* __restrict__ bnpq,
    const float* __restrict__ bnpsIn, const float* __restrict__ bnpqIn,
    const float* __restrict__ gIn, const float* __restrict__ bshIn,
    float* __restrict__ scOut, float* __restrict__ shOut,
    int M, int Nn, int K, int aMode, int storeMode, int relu, int bnstat,
    int bnfin)
{
    __shared__ ushort As[64][LDP];
    __shared__ ushort Bs[64][LDP];
    __shared__ float sRedS[8][64];
    __shared__ float sRedQ[8][64];
    float* sSc = &sRedS[0][0];   // alias (bnfin path only; bnstat==0 then)
    float* sSh = &sRedQ[0][0];
    int tid = threadIdx.x;
    int lane = tid & 63, w = tid >> 6;
    int wm = (w >> 1) * 32, wn = (w & 1) * 32;
    int nbx = gridDim.x, nbyq = gridDim.y >> 3;
    int orig = blockIdx.y * nbx + blockIdx.x;
    int xcd = orig & 7, pos = orig >> 3;
    int by = xcd * nbyq + pos / nbx;
    int bx = pos % nbx;
    int m0 = by * 64, n0 = bx * 64;
    int l15 = lane & 15, lk = lane >> 4;
    int srow = tid >> 3;
    int scol = (tid & 7) * 8;

    if (bnfin) {
        float s = 0.f, q = 0.f;
        #pragma unroll 8
        for (int bb = 0; bb < 64; ++bb) {
            s += bnpsIn[bb * DIM + tid];
            q += bnpqIn[bb * DIM + tid];
        }
        float m = s * (1.f / NN);
        float var = q * (1.f / NN) - m * m;
        float sc = rsqrtf(var + EPS_BN) * gIn[tid];
        float sh = bshIn[tid] - m * sc;
        sSc[tid] = sc;
        sSh[tid] = sh;
        scOut[tid] = sc;     // redundant identical writes (deterministic)
        shOut[tid] = sh;
        __syncthreads();
    }

    f32x4 acc[2][2] = {};
    for (int k0 = 0; k0 < K; k0 += 64) {
        uint4 ga0, ga1, gb0, gb1;
        const ushort* Bg = B + (size_t)(n0 + srow) * K + scol + k0;
        gb0 = *(const uint4*)Bg;
        gb1 = *(const uint4*)(Bg + (size_t)32 * K);
        if (aMode == 0) {
            const ushort* Ag = (const ushort*)Aptr + (size_t)(m0 + srow) * K + scol + k0;
            ga0 = *(const uint4*)Ag;
            ga1 = *(const uint4*)(Ag + (size_t)32 * K);
        } else if (aMode == 2) {
            int c0 = k0 + scol;
            int hh = c0 >> 5, dd = c0 & 31;
            const ushort* Ag = (const ushort*)Aptr +
                ((size_t)hh * NN + m0 + srow) * HDIM + dd;
            ga0 = *(const uint4*)Ag;
            ga1 = *(const uint4*)(Ag + (size_t)32 * HDIM);
        } else {
            const float* Af = (const float*)Aptr + (size_t)(m0 + srow) * K + scol + k0;
            float4 sc0 = *(const float4*)&sSc[k0 + scol];
            float4 sc1 = *(const float4*)&sSc[k0 + scol + 4];
            float4 sh0 = *(const float4*)&sSh[k0 + scol];
            float4 sh1 = *(const float4*)&sSh[k0 + scol + 4];
            float4 a0 = *(const float4*)Af;
            float4 a1 = *(const float4*)(Af + 4);
            float4 b0 = *(const float4*)(Af + (size_t)32 * K);
            float4 b1 = *(const float4*)(Af + (size_t)32 * K + 4);
            ga0.x = (unsigned)f2bf(a0.x*sc0.x+sh0.x) | ((unsigned)f2bf(a0.y*sc0.y+sh0.y) << 16);
            ga0.y = (unsigned)f2bf(a0.z*sc0.z+sh0.z) | ((unsigned)f2bf(a0.w*sc0.w+sh0.w) << 16);
            ga0.z = (unsigned)f2bf(a1.x*sc1.x+sh1.x) | ((unsigned)f2bf(a1.y*sc1.y+sh1.y) << 16);
            ga0.w = (unsigned)f2bf(a1.z*sc1.z+sh1.z) | ((unsigned)f2bf(a1.w*sc1.w+sh1.w) << 16);
            ga1.x = (unsigned)f2bf(b0.x*sc0.x+sh0.x) | ((unsigned)f2bf(b0.y*sc0.y+sh0.y) << 16);
            ga1.y = (unsigned)f2bf(b0.z*sc0.z+sh0.z) | ((unsigned)f2bf(b0.w*sc0.w+sh0.w) << 16);
            ga1.z = (unsigned)f2bf(b1.x*sc1.x+sh1.x) | ((unsigned)f2bf(b1.y*sc1.y+sh1.y) << 16);
            ga1.w = (unsigned)f2bf(b1.z*sc1.z+sh1.z) | ((unsigned)f2bf(b1.w*sc1.w+sh1.w) << 16);
        }
        __syncthreads();
        *(uint4*)&As[srow][scol]      = ga0;
        *(uint4*)&As[srow + 32][scol] = ga1;
        *(uint4*)&Bs[srow][scol]      = gb0;
        *(uint4*)&Bs[srow + 32][scol] = gb1;
        __syncthreads();
        #pragma unroll
        for (int ks = 0; ks < 2; ++ks) {
            int kc = ks * 32 + lk * 8;
            short8 a0 = *(const short8*)&As[wm      + l15][kc];
            short8 a1 = *(const short8*)&As[wm + 16 + l15][kc];
            short8 b0 = *(const short8*)&Bs[wn      + l15][kc];
            short8 b1 = *(const short8*)&Bs[wn + 16 + l15][kc];
            acc[0][0] = __builtin_amdgcn_mfma_f32_16x16x32_bf16(a0, b0, acc[0][0], 0, 0, 0);
            acc[0][1] = __builtin_amdgcn_mfma_f32_16x16x32_bf16(a0, b1, acc[0][1], 0, 0, 0);
            acc[1][0] = __builtin_amdgcn_mfma_f32_16x16x32_bf16(a1, b0, acc[1][0], 0, 0, 0);
            acc[1][1] = __builtin_amdgcn_mfma_f32_16x16x32_bf16(a1, b1, acc[1][1], 0, 0, 0);
        }
    }

    float sp[2] = {0.f, 0.f}, qp[2] = {0.f, 0.f};
    #pragma unroll
    for (int mt = 0; mt < 2; ++mt) {
        #pragma unroll
        for (int nt = 0; nt < 2; ++nt) {
            int col = n0 + wn + nt * 16 + l15;
            #pragma unroll
            for (int i = 0; i < 4; ++i) {
                int row = m0 + wm + mt * 16 + lk * 4 + i;
                float v = acc[mt][nt][i];
                if (storeMode == 0) {
                    if (resid) v += resid[(size_t)row * Nn + col];
                    Cf[(size_t)row * Nn + col] = v;
                } else if (storeMode == 1) {
                    if (relu) v = fmaxf(v, 0.f);
                    Cb[(size_t)row * Nn + col] = f2bf(v);
                } else { // 3
                    v += yres[(size_t)row * Nn + col] * scR[col] + shR[col];
                    Cf[(size_t)row * Nn + col] = v;
                }
                if (bnstat) { sp[nt] += v; qp[nt] += v * v; }
            }
        }
    }
    if (bnstat) {
        int slot = ((wm >> 5) << 2) | lk;
        __syncthreads();
        sRedS[slot][wn + l15]      = sp[0];
        sRedQ[slot][wn + l15]      = qp[0];
        sRedS[slot][wn + 16 + l15] = sp[1];
        sRedQ[slot][wn + 16 + l15] = qp[1];
        __syncthreads();
        if (tid < 64) {
            float ss = 0.f, qq = 0.f;
            #pragma unroll
            for (int r = 0; r < 8; ++r) { ss += sRedS[r][tid]; qq += sRedQ[r][tid]; }
            bnps[(size_t)by * DIM + n0 + tid] = ss;
            bnpq[(size_t)by * DIM + n0 + tid] = qq;
        }
    }
}

// ---------------- BN2 finalize + apply (per-block redundant finalize) ------
__global__ __launch_bounds__(256) void bn2_fin(
    const float* __restrict__ y,
    const float* __restrict__ bnps, const float* __restrict__ bnpq,
    const float* __restrict__ g, const float* __restrict__ bsh,
    float* __restrict__ out)
{
    __shared__ float sSc[256], sSh[256];
    int tid = threadIdx.x, b = blockIdx.x;
    {
        float s = 0.f, q = 0.f;
        #pragma unroll 8
        for (int bb = 0; bb < 64; ++bb) {
            s += bnps[bb * DIM + tid];
            q += bnpq[bb * DIM + tid];
        }
        float m = s * (1.f / NN);
        float var = q * (1.f / NN) - m * m;
        float sc = rsqrtf(var + EPS_BN) * g[tid];
        sSc[tid] = sc;
        sSh[tid] = bsh[tid] - m * sc;
    }
    __syncthreads();
    int c4 = (tid & 63) * 4;
    float4 sc = *(float4*)&sSc[c4];
    float4 sh = *(float4*)&sSh[c4];
    #pragma unroll
    for (int it = 0; it < 2; ++it) {
        size_t i4 = (size_t)b * 512 + it * 256 + tid;   // float4 index
        float4 v = ((const float4*)y)[i4];
        float4 r;
        r.x = v.x * sc.x + sh.x;
        r.y = v.y * sc.y + sh.y;
        r.z = v.z * sc.z + sh.z;
        r.w = v.w * sc.w + sh.w;
        ((float4*)out)[i4] = r;
    }
}

// ---------------- attn5: wave-per-row head-partitioned attention -----------
// 8192 blocks: head hH = b&7 (XCD-local), rows rg*4..rg*4+3; wave r = 1 row.
// Phase 1: 64-lane j-split (1 iter for nnz<=64). Phase 2: 8-way j-split
// (jsub = l>>3) x 8 dq lanes, uint2 gathers, 2-way unrolled; 64-wide
// shuffle reduces. L2-resident per-XCD working set (~768 KB/head).
__global__ __launch_bounds__(256) void attn5(
    const ushort* __restrict__ qh, const ushort* __restrict__ kvh,
    const float* __restrict__ vsumh,
    const unsigned* __restrict__ packed, const int* __restrict__ cnt,
    ushort* __restrict__ outh)
{
    __shared__ unsigned sPk[4][CAP];   // 2 KB
    __shared__ float    sS[4][CAP];    // 2 KB

    int tid = threadIdx.x, b = blockIdx.x;
    int hH = b & 7, rg = b >> 3;
    int r = tid >> 6, l = tid & 63;    // wave r owns row n
    int n = rg * 4 + r;
    int nnz = cnt[n];

    // q row (64B) broadcast-loaded into per-lane packed regs
    const uint4* qp4 = (const uint4*)(qh + ((size_t)hH * NN + n) * HDIM);
    uint4 q0 = qp4[0], q1 = qp4[1], q2 = qp4[2], q3 = qp4[3];
    for (int j = l; j < nnz; j += 64) sPk[r][j] = packed[n * CAP + j];
    __syncthreads();

    // phase 1: scores + weights (lane j), denom via 64-wide butterfly
    float lsum = 0.0f;
    for (int j = l; j < nnz; j += 64) {
        unsigned pk = sPk[r][j];
        int m = pk & 0xFFFF;
        float a = bfhi(pk);
        const uint4* kp = (const uint4*)(kvh + ((size_t)hH * NN + m) * 64);
        uint4 k0 = kp[0], k1 = kp[1], k2 = kp[2], k3 = kp[3];
        float s =
            bflo(k0.x)*bflo(q0.x) + bfhi(k0.x)*bfhi(q0.x) +
            bflo(k0.y)*bflo(q0.y) + bfhi(k0.y)*bfhi(q0.y) +
            bflo(k0.z)*bflo(q0.z) + bfhi(k0.z)*bfhi(q0.z) +
            bflo(k0.w)*bflo(q0.w) + bfhi(k0.w)*bfhi(q0.w) +
            bflo(k1.x)*bflo(q1.x) + bfhi(k1.x)*bfhi(q1.x) +
            bflo(k1.y)*bflo(q1.y) + bfhi(k1.y)*bfhi(q1.y) +
            bflo(k1.z)*bflo(q1.z) + bfhi(k1.z)*bfhi(q1.z) +
            bflo(k1.w)*bflo(q1.w) + bfhi(k1.w)*bfhi(q1.w) +
            bflo(k2.x)*bflo(q2.x) + bfhi(k2.x)*bfhi(q2.x) +
            bflo(k2.y)*bflo(q2.y) + bfhi(k2.y)*bfhi(q2.y) +
            bflo(k2.z)*bflo(q2.z) + bfhi(k2.z)*bfhi(q2.z) +
            bflo(k2.w)*bflo(q2.w) + bfhi(k2.w)*bfhi(q2.w) +
            bflo(k3.x)*bflo(q3.x) + bfhi(k3.x)*bfhi(q3.x) +
            bflo(k3.y)*bflo(q3.y) + bfhi(k3.y)*bfhi(q3.y) +
            bflo(k3.z)*bflo(q3.z) + bfhi(k3.z)*bfhi(q3.z) +
            bflo(k3.w)*bflo(q3.w) + bfhi(k3.w)*bfhi(q3.w);
        s *= a;
        float ww = __expf(s);
        sS[r][j] = ww - 1.0f;
        lsum += ww;
    }
    #pragma unroll
    for (int o = 32; o > 0; o >>= 1) lsum += __shfl_xor(lsum, o, 64);
    float rd = 1.0f / (lsum + (float)(NN - nnz));
    __syncthreads();

    // phase 2: lane = (jsub = l>>3, dq = l&7); 8-way j split, 2-way unroll
    int jsub = l >> 3, dq = l & 7;
    const ushort* vbase = kvh + (size_t)hH * NN * 64 + 32 + dq * 4;
    float a0 = 0.f, a1 = 0.f, a2 = 0.f, a3 = 0.f;
    int j = jsub;
    for (; j + 8 < nnz; j += 16) {
        float w1 = sS[r][j];
        float w2 = sS[r][j + 8];
        int m1 = sPk[r][j] & 0xFFFF;
        int m2 = sPk[r][j + 8] & 0xFFFF;
        uint2 v1 = *(const uint2*)(vbase + (size_t)m1 * 64);
        uint2 v2 = *(const uint2*)(vbase + (size_t)m2 * 64);
        a0 += w1 * bflo(v1.x) + w2 * bflo(v2.x);
        a1 += w1 * bfhi(v1.x) + w2 * bfhi(v2.x);
        a2 += w1 * bflo(v1.y) + w2 * bflo(v2.y);
        a3 += w1 * bfhi(v1.y) + w2 * bfhi(v2.y);
    }
    if (j < nnz) {
        float w1 = sS[r][j];
        int m1 = sPk[r][j] & 0xFFFF;
        uint2 v1 = *(const uint2*)(vbase + (size_t)m1 * 64);
        a0 += w1 * bflo(v1.x);
        a1 += w1 * bfhi(v1.x);
        a2 += w1 * bflo(v1.y);
        a3 += w1 * bfhi(v1.y);
    }
    #pragma unroll
    for (int o = 8; o < 64; o <<= 1) {
        a0 += __shfl_xor(a0, o, 64);
        a1 += __shfl_xor(a1, o, 64);
        a2 += __shfl_xor(a2, o, 64);
        a3 += __shfl_xor(a3, o, 64);
    }
    if (jsub == 0) {
        int d0 = dq * 4;
        const float* vs = vsumh + hH * HDIM + d0;
        float r0 = (a0 + vs[0]) * rd;
        float r1 = (a1 + vs[1]) * rd;
        float r2 = (a2 + vs[2]) * rd;
        float r3 = (a3 + vs[3]) * rd;
        uint2 st;
        st.x = (unsigned)f2bf(r0) | ((unsigned)f2bf(r1) << 16);
        st.y = (unsigned)f2bf(r2) | ((unsigned)f2bf(r3) << 16);
        *(uint2*)(outh + ((size_t)hH * NN + n) * HDIM + d0) = st;
    }
}

// ---------------------------------------------------------------------------
extern "C" void kernel_launch(void* const* d_in, const int* in_sizes, int n_in,
                              void* d_out, int out_size, void* d_ws, size_t ws_size,
                              hipStream_t stream)
{
    const float* A  = (const float*)d_in[0];
    const float* h  = (const float*)d_in[1];
    const float* Wq = (const float*)d_in[2];
    const float* Wk = (const float*)d_in[3];
    const float* Wv = (const float*)d_in[4];
    const float* Wo = (const float*)d_in[5];
    const float* g1 = (const float*)d_in[6];
    const float* b1 = (const float*)d_in[7];
    const float* g2 = (const float*)d_in[8];
    const float* b2 = (const float*)d_in[9];
    const float* W1 = (const float*)d_in[10];
    const float* W2 = (const float*)d_in[11];
    float* out = (float*)d_out;
    char* w = (char*)d_ws;

    unsigned* packed = (unsigned*)(w);           // [0,2M)  nz lists
    int*    nzcnt  = (int*)(w + 2 * MB);
    ushort* wqkv   = (ushort*)(w + 5 * MB);      // 384 KB
    ushort* wo_b   = (ushort*)(w + 5 * MB + 384 * 1024);   // k-permuted Wo
    ushort* w1_b   = (ushort*)(w + 5 * MB + 512 * 1024);
    ushort* w2_b   = (ushort*)(w + 5 * MB + 768 * 1024);
    ushort* qh_bf  = (ushort*)(w + 6 * MB);      // 2 MB [8][4096][32]
    ushort* kvh    = (ushort*)(w + 8 * MB);      // 4 MB [8][4096][64] k|v
    ushort* ao_hb  = (ushort*)(w + 12 * MB);     // 2 MB [8][4096][32] head-major
    float*  y      = (float*)(w + 14 * MB);      // 4 MB
    ushort* t_bf   = (ushort*)(w + 18 * MB);     // 4 MB FFN hidden
    float*  vpart  = (float*)(w + 22 * MB);      // 64 KB [64][256]
    float*  bnps   = (float*)(w + 23 * MB);
    float*  bnpq   = (float*)(w + 23 * MB + 64 * 1024);
    float*  scale1 = (float*)(w + 24 * MB);
    float*  shift1 = scale1 + 256;
    float*  vsumh  = scale1 + 1024;

    dim3 blk(256);

    // 1: weight conversions (Wo k-permuted)
    convert_w<<<256, blk, 0, stream>>>(Wq, Wk, Wv, Wo, W1, W2,
                                       wqkv, wo_b, w1_b, w2_b);
    // 2: fused QKV gemm (fp32 h converted on-load) + A nz-scan
    qkv_ascan<<<4864, blk, 0, stream>>>(h, wqkv, qh_bf, kvh, vpart,
                                        A, packed, nzcnt);
    // 3: vsumh (tiny, coalesced)
    vsum_final<<<1, blk, 0, stream>>>(vpart, vsumh);
    // 4: wave-per-row head-partitioned attention -> ao_hb
    attn5<<<8192, blk, 0, stream>>>(qh_bf, kvh, vsumh, packed, nzcnt, ao_hb);
    // 5: Wo projection + residual(h) -> y, with BN1 stat partials
    gemm_bf<<<dim3(4, 64), blk, 0, stream>>>(ao_hb, wo_b,
        h, nullptr, nullptr, nullptr,
        y, nullptr, bnps, bnpq,
        nullptr, nullptr, nullptr, nullptr, nullptr, nullptr,
        NN, DIM, DIM, 2, 0, 0, 1, 0);
    // 6: FFN1 — per-block BN1 finalize + on-load BN + relu
    gemm_bf<<<dim3(8, 64), blk, 0, stream>>>(y, w1_b,
        nullptr, nullptr, nullptr, nullptr,
        nullptr, t_bf, nullptr, nullptr,
        bnps, bnpq, g1, b1, scale1, shift1,
        NN, DFF, DIM, 1, 1, 1, 0, 1);
    // 7: FFN2 + recomputed BN1 residual (scale1/shift1 from FFN1), BN2 partials
    gemm_bf<<<dim3(4, 64), blk, 0, stream>>>(t_bf, w2_b,
        nullptr, y, scale1, shift1,
        y, nullptr, bnps, bnpq,
        nullptr, nullptr, nullptr, nullptr, nullptr, nullptr,
        NN, DIM, DFF, 0, 3, 0, 1, 0);
    // 8: BN2 finalize (per-block) + apply -> d_out
    bn2_fin<<<512, blk, 0, stream>>>(y, bnps, bnpq, g2, b2, out);
}

// Round 16
// 90.711 us; speedup vs baseline: 1.0256x; 1.0256x over previous
//
#include <hip/hip_runtime.h>
#include <math.h>

#define NN 4096        // nodes
#define DIM 256        // hidden
#define NHEAD 8
#define HDIM 32
#define DFF 512
#define CAP 128        // max nonzeros per row (mean ~41, max ~75 at p=.01)
#define EPS_BN 1e-5f
#define QSCALE 0.0625f // D^-0.5
#define MB (1u << 20)

typedef __attribute__((ext_vector_type(8))) short short8;
typedef __attribute__((ext_vector_type(4))) float f32x4;

__device__ inline ushort f2bf(float x) {   // RNE float->bf16
    unsigned u = __builtin_bit_cast(unsigned, x);
    unsigned r = u + 0x7FFF + ((u >> 16) & 1);
    return (ushort)(r >> 16);
}
__device__ inline float bf2f(ushort u) {
    return __builtin_bit_cast(float, (unsigned)u << 16);
}
__device__ inline float bflo(unsigned u) { return __builtin_bit_cast(float, u << 16); }
__device__ inline float bfhi(unsigned u) { return __builtin_bit_cast(float, u & 0xFFFF0000u); }
__device__ inline uint4 pack8(float4 a, float4 b) {
    uint4 u;
    u.x = (unsigned)f2bf(a.x) | ((unsigned)f2bf(a.y) << 16);
    u.y = (unsigned)f2bf(a.z) | ((unsigned)f2bf(a.w) << 16);
    u.z = (unsigned)f2bf(b.x) | ((unsigned)f2bf(b.y) << 16);
    u.w = (unsigned)f2bf(b.z) | ((unsigned)f2bf(b.w) << 16);
    return u;
}

// ---------------- fused: QKV gemm (blocks 0..767) + A nz-scan (768..4863) --
// GEMM: A = fp32 h converted on load; B = fp32 Wq/Wk/Wv (seg = n0>>8)
// converted on load (L2-resident re-reads). No fences, no atomics.
#define LDP 88
#define TSTRIDE 74
__global__ __launch_bounds__(256) void qkv_ascan(
    const float* __restrict__ hF,
    const float* __restrict__ Wq, const float* __restrict__ Wk,
    const float* __restrict__ Wv,
    ushort* __restrict__ qh, ushort* __restrict__ kvh,
    float* __restrict__ vpart,
    const float* __restrict__ Araw, unsigned* __restrict__ packed,
    int* __restrict__ cnt)
{
    __shared__ ushort As[64][LDP];
    __shared__ ushort Bs[64][LDP];
    __shared__ float sRedS[8][64];
    int b = blockIdx.x, tid = threadIdx.x;

    if (b >= 768) {
        // ---- A-scan branch ----
        int* scan = (int*)&As[0][0];
        int n = b - 768;
        const float* row = Araw + (size_t)n * NN;
        float4 vals[4];
        int c = 0;
        #pragma unroll
        for (int i = 0; i < 4; ++i) {
            vals[i] = *(const float4*)(row + i * 1024 + tid * 4);
            c += (vals[i].x != 0.f) + (vals[i].y != 0.f)
               + (vals[i].z != 0.f) + (vals[i].w != 0.f);
        }
        scan[tid] = c;
        __syncthreads();
        for (int off = 1; off < 256; off <<= 1) {
            int t = (tid >= off) ? scan[tid - off] : 0;
            __syncthreads();
            scan[tid] += t;
            __syncthreads();
        }
        int pos = scan[tid] - c;       // exclusive prefix
        int total = scan[255];
        #pragma unroll
        for (int i = 0; i < 4; ++i) {
            int cb = i * 1024 + tid * 4;
            float4 v = vals[i];
            if (v.x != 0.f && pos < CAP) { packed[n*CAP+pos] = ((unsigned)f2bf(v.x) << 16) | (unsigned)cb;       ++pos; }
            if (v.y != 0.f && pos < CAP) { packed[n*CAP+pos] = ((unsigned)f2bf(v.y) << 16) | (unsigned)(cb + 1); ++pos; }
            if (v.z != 0.f && pos < CAP) { packed[n*CAP+pos] = ((unsigned)f2bf(v.z) << 16) | (unsigned)(cb + 2); ++pos; }
            if (v.w != 0.f && pos < CAP) { packed[n*CAP+pos] = ((unsigned)f2bf(v.w) << 16) | (unsigned)(cb + 3); ++pos; }
        }
        if (tid == 0) cnt[n] = min(total, CAP);
        return;
    }

    // ---- QKV GEMM branch ----
    int lane = tid & 63, w = tid >> 6;
    int wm = (w >> 1) * 32, wn = (w & 1) * 32;
    int xcd = b & 7, pos = b >> 3;
    int by = xcd * 8 + pos / 12;
    int bx = pos % 12;
    int m0 = by * 64, n0 = bx * 64;
    int seg = n0 >> 8;                  // 0:q 1:k 2:v (64-row panel in one seg)
    const float* Wsrc = (seg == 0) ? Wq : ((seg == 1) ? Wk : Wv);
    int l15 = lane & 15, lk = lane >> 4;
    int srow = tid >> 3;
    int scol = (tid & 7) * 8;

    f32x4 acc[2][2] = {};
    for (int k0 = 0; k0 < DIM; k0 += 64) {
        const float* Bf = Wsrc + (size_t)((n0 & 255) + srow) * DIM + scol + k0;
        uint4 gb0 = pack8(*(const float4*)Bf, *(const float4*)(Bf + 4));
        uint4 gb1 = pack8(*(const float4*)(Bf + (size_t)32 * DIM),
                          *(const float4*)(Bf + (size_t)32 * DIM + 4));
        const float* Af = hF + (size_t)(m0 + srow) * DIM + scol + k0;
        uint4 ga0 = pack8(*(const float4*)Af, *(const float4*)(Af + 4));
        uint4 ga1 = pack8(*(const float4*)(Af + (size_t)32 * DIM),
                          *(const float4*)(Af + (size_t)32 * DIM + 4));
        __syncthreads();
        *(uint4*)&As[srow][scol]      = ga0;
        *(uint4*)&As[srow + 32][scol] = ga1;
        *(uint4*)&Bs[srow][scol]      = gb0;
        *(uint4*)&Bs[srow + 32][scol] = gb1;
        __syncthreads();
        #pragma unroll
        for (int ks = 0; ks < 2; ++ks) {
            int kc = ks * 32 + lk * 8;
            short8 a0s = *(const short8*)&As[wm      + l15][kc];
            short8 a1s = *(const short8*)&As[wm + 16 + l15][kc];
            short8 b0s = *(const short8*)&Bs[wn      + l15][kc];
            short8 b1s = *(const short8*)&Bs[wn + 16 + l15][kc];
            acc[0][0] = __builtin_amdgcn_mfma_f32_16x16x32_bf16(a0s, b0s, acc[0][0], 0, 0, 0);
            acc[0][1] = __builtin_amdgcn_mfma_f32_16x16x32_bf16(a0s, b1s, acc[0][1], 0, 0, 0);
            acc[1][0] = __builtin_amdgcn_mfma_f32_16x16x32_bf16(a1s, b0s, acc[1][0], 0, 0, 0);
            acc[1][1] = __builtin_amdgcn_mfma_f32_16x16x32_bf16(a1s, b1s, acc[1][1], 0, 0, 0);
        }
    }
    // transpose via LDS (reuse As), coalesced 16B chunk stores
    ushort* sT = &As[0][0];
    int ddBase = (n0 & 255) >> 3;
    float sp[2] = {0.f, 0.f};
    __syncthreads();
    #pragma unroll
    for (int mt = 0; mt < 2; ++mt)
        #pragma unroll
        for (int nt = 0; nt < 2; ++nt) {
            int col_l = wn + nt * 16 + l15;
            #pragma unroll
            for (int i = 0; i < 4; ++i) {
                int row_l = wm + mt * 16 + lk * 4 + i;
                float v = acc[mt][nt][i];
                if (seg == 0) v *= QSCALE;
                sT[row_l * TSTRIDE + col_l] = f2bf(v);
                sp[nt] += v;
            }
        }
    __syncthreads();
    for (int c = tid; c < 512; c += 256) {
        int rl = c & 63, hh = c >> 6;
        const ushort* tp = sT + rl * TSTRIDE + hh;
        uint4 pk;
        pk.x = (unsigned)tp[0]  | ((unsigned)tp[8]  << 16);
        pk.y = (unsigned)tp[16] | ((unsigned)tp[24] << 16);
        pk.z = (unsigned)tp[32] | ((unsigned)tp[40] << 16);
        pk.w = (unsigned)tp[48] | ((unsigned)tp[56] << 16);
        int row = m0 + rl;
        if (seg == 0)
            *(uint4*)(qh + ((size_t)hh * NN + row) * HDIM + ddBase) = pk;
        else
            *(uint4*)(kvh + ((size_t)hh * NN + row) * 64 +
                      ((seg == 2) ? 32 : 0) + ddBase) = pk;
    }
    if (seg == 2) {
        int slot = ((wm >> 5) << 2) | lk;
        sRedS[slot][wn + l15]      = sp[0];
        sRedS[slot][wn + 16 + l15] = sp[1];
        __syncthreads();
        if (tid < 64) {
            float ss = 0.f;
            #pragma unroll
            for (int r = 0; r < 8; ++r) ss += sRedS[r][tid];
            vpart[(size_t)by * 256 + (n0 & 255) + tid] = ss;
        }
    }
}

// ---------------- vsum final (block 0) + Wo permuted convert (1..32) -------
__global__ __launch_bounds__(256) void vsum_wo(
    const float* __restrict__ vpart, float* __restrict__ vsumh,
    const float* __restrict__ Wo, ushort* __restrict__ wo_b)
{
    int b = blockIdx.x, tid = threadIdx.x;
    if (b == 0) {
        float s = 0.f;
        #pragma unroll 8
        for (int bb = 0; bb < 64; ++bb) s += vpart[(size_t)bb * 256 + tid];
        vsumh[(tid & 7) * HDIM + (tid >> 3)] = s;
        return;
    }
    // Wo permuted convert: dest[row][h*32+d] = src[row][d*8+h]
    int off = b - 1;
    int row = off * 8 + (tid >> 5), t = tid & 31;
    int hh = t >> 2, dd0 = (t & 3) * 8;
    const float* src = Wo + (size_t)row * 256 + hh;
    ushort tmp[8];
    #pragma unroll
    for (int i = 0; i < 8; ++i) tmp[i] = f2bf(src[(size_t)(dd0 + i) * 8]);
    uint4 u;
    u.x = (unsigned)tmp[0] | ((unsigned)tmp[1] << 16);
    u.y = (unsigned)tmp[2] | ((unsigned)tmp[3] << 16);
    u.z = (unsigned)tmp[4] | ((unsigned)tmp[5] << 16);
    u.w = (unsigned)tmp[6] | ((unsigned)tmp[7] << 16);
    *(uint4*)(wo_b + (size_t)row * 256 + hh * 32 + dd0) = u;
}

// ---------------- bf16 MFMA GEMM, XCD-swizzled -----------------------------
// aMode 0: A bf16 [M,K]. aMode 1: A fp32 + on-load BN (scale/shift from LDS,
//   computed in prologue when bnfin=1). aMode 2: A bf16 head-major.
// bMode 0: B bf16 [Nn,K]. bMode 1: B fp32 [Nn,K] converted on load.
// storeMode 0: Cf fp32 (+resid). 1: Cb bf16 (relu opt).
//   3: Cf fp32, residual recomputed as yres*scR+shR (Cf may alias yres).
// bnstat: per-block col sum/sumsq partials -> bnps/bnpq [nby][256].
// bnfin: prologue reduces bnpsIn/bnpqIn + gIn/bshIn -> LDS scale/shift,
//   and redundantly writes scOut/shOut (identical bits from every block).
__global__ __launch_bounds__(256) void gemm_bf(
    const void* __restrict__ Aptr, const void* __restrict__ Bptr,
    const float* __restrict__ resid,
    const float* yres, const float* __restrict__ scR, const float* __restrict__ shR,
    float* Cf, ushort* __restrict__ Cb,
    float* __restrict__ bnps, float* __restrict__ bnpq,
    const float* __restrict__ bnpsIn, const float* __restrict__ bnpqIn,
    const float* __restrict__ gIn, const float* __restrict__ bshIn,
    float* __restrict__ scOut, float* __restrict__ shOut,
    int M, int Nn, int K, int aMode, int bMode, int storeMode, int relu,
    int bnstat, int bnfin)
{
    __shared__ ushort As[64][LDP];
    __shared__ ushort Bs[64][LDP];
    __shared__ float sRedS[8][64];
    __shared__ float sRedQ[8][64];
    float* sSc = &sRedS[0][0];   // alias (bnfin path only; bnstat==0 then)
    float* sSh = &sRedQ[0][0];
    int tid = threadIdx.x;
    int lane = tid & 63, w = tid >> 6;
    int wm = (w >> 1) * 32, wn = (w & 1) * 32;
    int nbx = gridDim.x, nbyq = gridDim.y >> 3;
    int orig = blockIdx.y * nbx + blockIdx.x;
    int xcd = orig & 7, pos = orig >> 3;
    int by = xcd * nbyq + pos / nbx;
    int bx = pos % nbx;
    int m0 = by * 64, n0 = bx * 64;
    int l15 = lane & 15, lk = lane >> 4;
    int srow = tid >> 3;
    int scol = (tid & 7) * 8;

    if (bnfin) {
        float s = 0.f, q = 0.f;
        #pragma unroll 8
        for (int bb = 0; bb < 64; ++bb) {
            s += bnpsIn[bb * DIM + tid];
            q += bnpqIn[bb * DIM + tid];
        }
        float m = s * (1.f / NN);
        float var = q * (1.f / NN) - m * m;
        float sc = rsqrtf(var + EPS_BN) * gIn[tid];
        float sh = bshIn[tid] - m * sc;
        sSc[tid] = sc;
        sSh[tid] = sh;
        scOut[tid] = sc;     // redundant identical writes (deterministic)
        shOut[tid] = sh;
        __syncthreads();
    }

    f32x4 acc[2][2] = {};
    for (int k0 = 0; k0 < K; k0 += 64) {
        uint4 ga0, ga1, gb0, gb1;
        if (bMode == 0) {
            const ushort* Bg = (const ushort*)Bptr + (size_t)(n0 + srow) * K + scol + k0;
            gb0 = *(const uint4*)Bg;
            gb1 = *(const uint4*)(Bg + (size_t)32 * K);
        } else {
            const float* Bf = (const float*)Bptr + (size_t)(n0 + srow) * K + scol + k0;
            gb0 = pack8(*(const float4*)Bf, *(const float4*)(Bf + 4));
            gb1 = pack8(*(const float4*)(Bf + (size_t)32 * K),
                        *(const float4*)(Bf + (size_t)32 * K + 4));
        }
        if (aMode == 0) {
            const ushort* Ag = (const ushort*)Aptr + (size_t)(m0 + srow) * K + scol + k0;
            ga0 = *(const uint4*)Ag;
            ga1 = *(const uint4*)(Ag + (size_t)32 * K);
        } else if (aMode == 2) {
            int c0 = k0 + scol;
            int hh = c0 >> 5, dd = c0 & 31;
            const ushort* Ag = (const ushort*)Aptr +
                ((size_t)hh * NN + m0 + srow) * HDIM + dd;
            ga0 = *(const uint4*)Ag;
            ga1 = *(const uint4*)(Ag + (size_t)32 * HDIM);
        } else {
            const float* Af = (const float*)Aptr + (size_t)(m0 + srow) * K + scol + k0;
            float4 sc0 = *(const float4*)&sSc[k0 + scol];
            float4 sc1 = *(const float4*)&sSc[k0 + scol + 4];
            float4 sh0 = *(const float4*)&sSh[k0 + scol];
            float4 sh1 = *(const float4*)&sSh[k0 + scol + 4];
            float4 a0 = *(const float4*)Af;
            float4 a1 = *(const float4*)(Af + 4);
            float4 b0 = *(const float4*)(Af + (size_t)32 * K);
            float4 b1 = *(const float4*)(Af + (size_t)32 * K + 4);
            float4 p0, p1;
            p0.x = a0.x*sc0.x+sh0.x; p0.y = a0.y*sc0.y+sh0.y;
            p0.z = a0.z*sc0.z+sh0.z; p0.w = a0.w*sc0.w+sh0.w;
            p1.x = a1.x*sc1.x+sh1.x; p1.y = a1.y*sc1.y+sh1.y;
            p1.z = a1.z*sc1.z+sh1.z; p1.w = a1.w*sc1.w+sh1.w;
            ga0 = pack8(p0, p1);
            p0.x = b0.x*sc0.x+sh0.x; p0.y = b0.y*sc0.y+sh0.y;
            p0.z = b0.z*sc0.z+sh0.z; p0.w = b0.w*sc0.w+sh0.w;
            p1.x = b1.x*sc1.x+sh1.x; p1.y = b1.y*sc1.y+sh1.y;
            p1.z = b1.z*sc1.z+sh1.z; p1.w = b1.w*sc1.w+sh1.w;
            ga1 = pack8(p0, p1);
        }
        __syncthreads();
        *(uint4*)&As[srow][scol]      = ga0;
        *(uint4*)&As[srow + 32][scol] = ga1;
        *(uint4*)&Bs[srow][scol]      = gb0;
        *(uint4*)&Bs[srow + 32][scol] = gb1;
        __syncthreads();
        #pragma unroll
        for (int ks = 0; ks < 2; ++ks) {
            int kc = ks * 32 + lk * 8;
            short8 a0 = *(const short8*)&As[wm      + l15][kc];
            short8 a1 = *(const short8*)&As[wm + 16 + l15][kc];
            short8 b0 = *(const short8*)&Bs[wn      + l15][kc];
            short8 b1 = *(const short8*)&Bs[wn + 16 + l15][kc];
            acc[0][0] = __builtin_amdgcn_mfma_f32_16x16x32_bf16(a0, b0, acc[0][0], 0, 0, 0);
            acc[0][1] = __builtin_amdgcn_mfma_f32_16x16x32_bf16(a0, b1, acc[0][1], 0, 0, 0);
            acc[1][0] = __builtin_amdgcn_mfma_f32_16x16x32_bf16(a1, b0, acc[1][0], 0, 0, 0);
            acc[1][1] = __builtin_amdgcn_mfma_f32_16x16x32_bf16(a1, b1, acc[1][1], 0, 0, 0);
        }
    }

    float sp[2] = {0.f, 0.f}, qp[2] = {0.f, 0.f};
    #pragma unroll
    for (int mt = 0; mt < 2; ++mt) {
        #pragma unroll
        for (int nt = 0; nt < 2; ++nt) {
            int col = n0 + wn + nt * 16 + l15;
            #pragma unroll
            for (int i = 0; i < 4; ++i) {
                int row = m0 + wm + mt * 16 + lk * 4 + i;
                float v = acc[mt][nt][i];
                if (storeMode == 0) {
                    if (resid) v += resid[(size_t)row * Nn + col];
                    Cf[(size_t)row * Nn + col] = v;
                } else if (storeMode == 1) {
                    if (relu) v = fmaxf(v, 0.f);
                    Cb[(size_t)row * Nn + col] = f2bf(v);
                } else { // 3
                    v += yres[(size_t)row * Nn + col] * scR[col] + shR[col];
                    Cf[(size_t)row * Nn + col] = v;
                }
                if (bnstat) { sp[nt] += v; qp[nt] += v * v; }
            }
        }
    }
    if (bnstat) {
        int slot = ((wm >> 5) << 2) | lk;
        __syncthreads();
        sRedS[slot][wn + l15]      = sp[0];
        sRedQ[slot][wn + l15]      = qp[0];
        sRedS[slot][wn + 16 + l15] = sp[1];
        sRedQ[slot][wn + 16 + l15] = qp[1];
        __syncthreads();
        if (tid < 64) {
            float ss = 0.f, qq = 0.f;
            #pragma unroll
            for (int r = 0; r < 8; ++r) { ss += sRedS[r][tid]; qq += sRedQ[r][tid]; }
            bnps[(size_t)by * DIM + n0 + tid] = ss;
            bnpq[(size_t)by * DIM + n0 + tid] = qq;
        }
    }
}

// ---------------- BN2 finalize + apply (per-block redundant finalize) ------
__global__ __launch_bounds__(256) void bn2_fin(
    const float* __restrict__ y,
    const float* __restrict__ bnps, const float* __restrict__ bnpq,
    const float* __restrict__ g, const float* __restrict__ bsh,
    float* __restrict__ out)
{
    __shared__ float sSc[256], sSh[256];
    int tid = threadIdx.x, b = blockIdx.x;
    {
        float s = 0.f, q = 0.f;
        #pragma unroll 8
        for (int bb = 0; bb < 64; ++bb) {
            s += bnps[bb * DIM + tid];
            q += bnpq[bb * DIM + tid];
        }
        float m = s * (1.f / NN);
        float var = q * (1.f / NN) - m * m;
        float sc = rsqrtf(var + EPS_BN) * g[tid];
        sSc[tid] = sc;
        sSh[tid] = bsh[tid] - m * sc;
    }
    __syncthreads();
    int c4 = (tid & 63) * 4;
    float4 sc = *(float4*)&sSc[c4];
    float4 sh = *(float4*)&sSh[c4];
    #pragma unroll
    for (int it = 0; it < 2; ++it) {
        size_t i4 = (size_t)b * 512 + it * 256 + tid;   // float4 index
        float4 v = ((const float4*)y)[i4];
        float4 r;
        r.x = v.x * sc.x + sh.x;
        r.y = v.y * sc.y + sh.y;
        r.z = v.z * sc.z + sh.z;
        r.w = v.w * sc.w + sh.w;
        ((float4*)out)[i4] = r;
    }
}

// ---------------- head-partitioned sparse masked attention (R9/R14 form) ---
__global__ __launch_bounds__(256) void attn3(
    const ushort* __restrict__ qh, const ushort* __restrict__ kvh,
    const float* __restrict__ vsumh,
    const unsigned* __restrict__ packed, const int* __restrict__ cnt,
    ushort* __restrict__ outh)
{
    __shared__ float    sQ[8][32];
    __shared__ unsigned sPk[8][CAP];
    __shared__ float    sS[8][CAP];
    __shared__ float    sRd[8];

    int tid = threadIdx.x, b = blockIdx.x;
    int hH = b & 7, rg = b >> 3;
    int r = tid >> 5, l = tid & 31;
    int n = rg * 8 + r;
    int nnz = cnt[n];

    sQ[r][l] = bf2f(qh[((size_t)hH * NN + n) * HDIM + l]);
    for (int j = l; j < nnz; j += 32) sPk[r][j] = packed[n * CAP + j];
    __syncthreads();

    // phase 1: scores + weights + denom (32 lanes split j within the row)
    float4 qreg[8];
    #pragma unroll
    for (int t = 0; t < 8; ++t) qreg[t] = ((const float4*)sQ[r])[t];
    float lsum = 0.0f;
    for (int j = l; j < nnz; j += 32) {
        unsigned pk = sPk[r][j];
        int m = pk & 0xFFFF;
        float a = bfhi(pk);
        const uint4* kp = (const uint4*)(kvh + ((size_t)hH * NN + m) * 64);
        uint4 k0 = kp[0], k1 = kp[1], k2 = kp[2], k3 = kp[3];
        float s =
            bflo(k0.x)*qreg[0].x + bfhi(k0.x)*qreg[0].y +
            bflo(k0.y)*qreg[0].z + bfhi(k0.y)*qreg[0].w +
            bflo(k0.z)*qreg[1].x + bfhi(k0.z)*qreg[1].y +
            bflo(k0.w)*qreg[1].z + bfhi(k0.w)*qreg[1].w +
            bflo(k1.x)*qreg[2].x + bfhi(k1.x)*qreg[2].y +
            bflo(k1.y)*qreg[2].z + bfhi(k1.y)*qreg[2].w +
            bflo(k1.z)*qreg[3].x + bfhi(k1.z)*qreg[3].y +
            bflo(k1.w)*qreg[3].z + bfhi(k1.w)*qreg[3].w +
            bflo(k2.x)*qreg[4].x + bfhi(k2.x)*qreg[4].y +
            bflo(k2.y)*qreg[4].z + bfhi(k2.y)*qreg[4].w +
            bflo(k2.z)*qreg[5].x + bfhi(k2.z)*qreg[5].y +
            bflo(k2.w)*qreg[5].z + bfhi(k2.w)*qreg[5].w +
            bflo(k3.x)*qreg[6].x + bfhi(k3.x)*qreg[6].y +
            bflo(k3.y)*qreg[6].z + bfhi(k3.y)*qreg[6].w +
            bflo(k3.z)*qreg[7].x + bfhi(k3.z)*qreg[7].y +
            bflo(k3.w)*qreg[7].z + bfhi(k3.w)*qreg[7].w;
        s *= a;
        float ww = __expf(s);
        sS[r][j] = ww - 1.0f;
        lsum += ww;
    }
    #pragma unroll
    for (int o = 16; o > 0; o >>= 1) lsum += __shfl_xor(lsum, o, 32);
    if (l == 0) sRd[r] = 1.0f / (lsum + (float)(NN - nnz));
    __syncthreads();

    // phase 2: lane = (jsub = l>>3, dq = l&7); 4-way j split, uint2 gathers
    int jsub = l >> 3, dq = l & 7;
    const ushort* vbase = kvh + (size_t)hH * NN * 64 + 32 + dq * 4;
    float a0 = 0.f, a1 = 0.f, a2 = 0.f, a3 = 0.f;
    for (int j = jsub; j < nnz; j += 4) {
        float ww = sS[r][j];
        int m = sPk[r][j] & 0xFFFF;
        uint2 vv = *(const uint2*)(vbase + (size_t)m * 64);
        a0 += ww * bflo(vv.x); a1 += ww * bfhi(vv.x);
        a2 += ww * bflo(vv.y); a3 += ww * bfhi(vv.y);
    }
    #pragma unroll
    for (int o = 8; o < 32; o <<= 1) {
        a0 += __shfl_xor(a0, o, 32);
        a1 += __shfl_xor(a1, o, 32);
        a2 += __shfl_xor(a2, o, 32);
        a3 += __shfl_xor(a3, o, 32);
    }
    if (jsub == 0) {
        float rd = sRd[r];
        int d0 = dq * 4;
        const float* vs = vsumh + hH * HDIM + d0;
        float r0 = (a0 + vs[0]) * rd;
        float r1 = (a1 + vs[1]) * rd;
        float r2 = (a2 + vs[2]) * rd;
        float r3 = (a3 + vs[3]) * rd;
        uint2 st;
        st.x = (unsigned)f2bf(r0) | ((unsigned)f2bf(r1) << 16);
        st.y = (unsigned)f2bf(r2) | ((unsigned)f2bf(r3) << 16);
        *(uint2*)(outh + ((size_t)hH * NN + n) * HDIM + d0) = st;
    }
}

// ---------------------------------------------------------------------------
extern "C" void kernel_launch(void* const* d_in, const int* in_sizes, int n_in,
                              void* d_out, int out_size, void* d_ws, size_t ws_size,
                              hipStream_t stream)
{
    const float* A  = (const float*)d_in[0];
    const float* h  = (const float*)d_in[1];
    const float* Wq = (const float*)d_in[2];
    const float* Wk = (const float*)d_in[3];
    const float* Wv = (const float*)d_in[4];
    const float* Wo = (const float*)d_in[5];
    const float* g1 = (const float*)d_in[6];
    const float* b1 = (const float*)d_in[7];
    const float* g2 = (const float*)d_in[8];
    const float* b2 = (const float*)d_in[9];
    const float* W1 = (const float*)d_in[10];
    const float* W2 = (const float*)d_in[11];
    float* out = (float*)d_out;
    char* w = (char*)d_ws;

    unsigned* packed = (unsigned*)(w);           // [0,2M)  nz lists
    int*    nzcnt  = (int*)(w + 2 * MB);
    ushort* wo_b   = (ushort*)(w + 5 * MB);      // 128 KB k-permuted Wo
    ushort* qh_bf  = (ushort*)(w + 6 * MB);      // 2 MB [8][4096][32]
    ushort* kvh    = (ushort*)(w + 8 * MB);      // 4 MB [8][4096][64] k|v
    ushort* ao_hb  = (ushort*)(w + 12 * MB);     // 2 MB [8][4096][32] head-major
    float*  y      = (float*)(w + 14 * MB);      // 4 MB
    ushort* t_bf   = (ushort*)(w + 18 * MB);     // 4 MB FFN hidden
    float*  vpart  = (float*)(w + 22 * MB);      // 64 KB [64][256]
    float*  bnps   = (float*)(w + 23 * MB);
    float*  bnpq   = (float*)(w + 23 * MB + 64 * 1024);
    float*  scale1 = (float*)(w + 24 * MB);
    float*  shift1 = scale1 + 256;
    float*  vsumh  = scale1 + 1024;

    dim3 blk(256);

    // 1: fused QKV gemm (h + Wq/Wk/Wv converted on load) + A nz-scan
    qkv_ascan<<<4864, blk, 0, stream>>>(h, Wq, Wk, Wv, qh_bf, kvh, vpart,
                                        A, packed, nzcnt);
    // 2: vsumh (block 0) + Wo permuted convert (blocks 1..32)
    vsum_wo<<<33, blk, 0, stream>>>(vpart, vsumh, Wo, wo_b);
    // 3: head-partitioned attention -> head-major ao_hb
    attn3<<<NN, blk, 0, stream>>>(qh_bf, kvh, vsumh, packed, nzcnt, ao_hb);
    // 4: Wo projection + residual(h) -> y, with BN1 stat partials
    gemm_bf<<<dim3(4, 64), blk, 0, stream>>>(ao_hb, wo_b,
        h, nullptr, nullptr, nullptr,
        y, nullptr, bnps, bnpq,
        nullptr, nullptr, nullptr, nullptr, nullptr, nullptr,
        NN, DIM, DIM, 2, 0, 0, 0, 1, 0);
    // 5: FFN1 — per-block BN1 finalize + on-load BN + relu (B = fp32 W1)
    gemm_bf<<<dim3(8, 64), blk, 0, stream>>>(y, W1,
        nullptr, nullptr, nullptr, nullptr,
        nullptr, t_bf, nullptr, nullptr,
        bnps, bnpq, g1, b1, scale1, shift1,
        NN, DFF, DIM, 1, 1, 1, 1, 0, 1);
    // 6: FFN2 + recomputed BN1 residual (B = fp32 W2), BN2 partials
    gemm_bf<<<dim3(4, 64), blk, 0, stream>>>(t_bf, W2,
        nullptr, y, scale1, shift1,
        y, nullptr, bnps, bnpq,
        nullptr, nullptr, nullptr, nullptr, nullptr, nullptr,
        NN, DIM, DFF, 0, 1, 3, 0, 1, 0);
    // 7: BN2 finalize (per-block) + apply -> d_out
    bn2_fin<<<512, blk, 0, stream>>>(y, bnps, bnpq, g2, b2, out);
}

// Round 17
// 88.595 us; speedup vs baseline: 1.0501x; 1.0239x over previous
//
#include <hip/hip_runtime.h>
#include <math.h>

#define NN 4096        // nodes
#define DIM 256        // hidden
#define NHEAD 8
#define HDIM 32
#define DFF 512
#define CAP 128        // max nonzeros per row (mean ~41, max ~75 at p=.01)
#define EPS_BN 1e-5f
#define QSCALE 0.0625f // D^-0.5
#define MB (1u << 20)

typedef __attribute__((ext_vector_type(8))) short short8;
typedef __attribute__((ext_vector_type(4))) float f32x4;

__device__ inline ushort f2bf(float x) {   // RNE float->bf16
    unsigned u = __builtin_bit_cast(unsigned, x);
    unsigned r = u + 0x7FFF + ((u >> 16) & 1);
    return (ushort)(r >> 16);
}
__device__ inline float bf2f(ushort u) {
    return __builtin_bit_cast(float, (unsigned)u << 16);
}
__device__ inline float bflo(unsigned u) { return __builtin_bit_cast(float, u << 16); }
__device__ inline float bfhi(unsigned u) { return __builtin_bit_cast(float, u & 0xFFFF0000u); }
__device__ inline uint4 pack8(float4 a, float4 b) {
    uint4 u;
    u.x = (unsigned)f2bf(a.x) | ((unsigned)f2bf(a.y) << 16);
    u.y = (unsigned)f2bf(a.z) | ((unsigned)f2bf(a.w) << 16);
    u.z = (unsigned)f2bf(b.x) | ((unsigned)f2bf(b.y) << 16);
    u.w = (unsigned)f2bf(b.z) | ((unsigned)f2bf(b.w) << 16);
    return u;
}

// ---------------- fused: QKV gemm (blocks 0..767) + A nz-scan (768..4863) --
// GEMM: A = fp32 h converted on load; B = fp32 Wq/Wk/Wv (seg = n0>>8)
// converted on load (L2-resident re-reads). v col-sum partials stored
// HEAD-MAJOR: vpart[by][h*32+d] (coalesced per-head slices for attn3).
#define LDP 88
#define TSTRIDE 74
__global__ __launch_bounds__(256) void qkv_ascan(
    const float* __restrict__ hF,
    const float* __restrict__ Wq, const float* __restrict__ Wk,
    const float* __restrict__ Wv,
    ushort* __restrict__ qh, ushort* __restrict__ kvh,
    float* __restrict__ vpart,
    const float* __restrict__ Araw, unsigned* __restrict__ packed,
    int* __restrict__ cnt)
{
    __shared__ ushort As[64][LDP];
    __shared__ ushort Bs[64][LDP];
    __shared__ float sRedS[8][64];
    int b = blockIdx.x, tid = threadIdx.x;

    if (b >= 768) {
        // ---- A-scan branch ----
        int* scan = (int*)&As[0][0];
        int n = b - 768;
        const float* row = Araw + (size_t)n * NN;
        float4 vals[4];
        int c = 0;
        #pragma unroll
        for (int i = 0; i < 4; ++i) {
            vals[i] = *(const float4*)(row + i * 1024 + tid * 4);
            c += (vals[i].x != 0.f) + (vals[i].y != 0.f)
               + (vals[i].z != 0.f) + (vals[i].w != 0.f);
        }
        scan[tid] = c;
        __syncthreads();
        for (int off = 1; off < 256; off <<= 1) {
            int t = (tid >= off) ? scan[tid - off] : 0;
            __syncthreads();
            scan[tid] += t;
            __syncthreads();
        }
        int pos = scan[tid] - c;       // exclusive prefix
        int total = scan[255];
        #pragma unroll
        for (int i = 0; i < 4; ++i) {
            int cb = i * 1024 + tid * 4;
            float4 v = vals[i];
            if (v.x != 0.f && pos < CAP) { packed[n*CAP+pos] = ((unsigned)f2bf(v.x) << 16) | (unsigned)cb;       ++pos; }
            if (v.y != 0.f && pos < CAP) { packed[n*CAP+pos] = ((unsigned)f2bf(v.y) << 16) | (unsigned)(cb + 1); ++pos; }
            if (v.z != 0.f && pos < CAP) { packed[n*CAP+pos] = ((unsigned)f2bf(v.z) << 16) | (unsigned)(cb + 2); ++pos; }
            if (v.w != 0.f && pos < CAP) { packed[n*CAP+pos] = ((unsigned)f2bf(v.w) << 16) | (unsigned)(cb + 3); ++pos; }
        }
        if (tid == 0) cnt[n] = min(total, CAP);
        return;
    }

    // ---- QKV GEMM branch ----
    int lane = tid & 63, w = tid >> 6;
    int wm = (w >> 1) * 32, wn = (w & 1) * 32;
    int xcd = b & 7, pos = b >> 3;
    int by = xcd * 8 + pos / 12;
    int bx = pos % 12;
    int m0 = by * 64, n0 = bx * 64;
    int seg = n0 >> 8;                  // 0:q 1:k 2:v (64-row panel in one seg)
    const float* Wsrc = (seg == 0) ? Wq : ((seg == 1) ? Wk : Wv);
    int l15 = lane & 15, lk = lane >> 4;
    int srow = tid >> 3;
    int scol = (tid & 7) * 8;

    f32x4 acc[2][2] = {};
    for (int k0 = 0; k0 < DIM; k0 += 64) {
        const float* Bf = Wsrc + (size_t)((n0 & 255) + srow) * DIM + scol + k0;
        uint4 gb0 = pack8(*(const float4*)Bf, *(const float4*)(Bf + 4));
        uint4 gb1 = pack8(*(const float4*)(Bf + (size_t)32 * DIM),
                          *(const float4*)(Bf + (size_t)32 * DIM + 4));
        const float* Af = hF + (size_t)(m0 + srow) * DIM + scol + k0;
        uint4 ga0 = pack8(*(const float4*)Af, *(const float4*)(Af + 4));
        uint4 ga1 = pack8(*(const float4*)(Af + (size_t)32 * DIM),
                          *(const float4*)(Af + (size_t)32 * DIM + 4));
        __syncthreads();
        *(uint4*)&As[srow][scol]      = ga0;
        *(uint4*)&As[srow + 32][scol] = ga1;
        *(uint4*)&Bs[srow][scol]      = gb0;
        *(uint4*)&Bs[srow + 32][scol] = gb1;
        __syncthreads();
        #pragma unroll
        for (int ks = 0; ks < 2; ++ks) {
            int kc = ks * 32 + lk * 8;
            short8 a0s = *(const short8*)&As[wm      + l15][kc];
            short8 a1s = *(const short8*)&As[wm + 16 + l15][kc];
            short8 b0s = *(const short8*)&Bs[wn      + l15][kc];
            short8 b1s = *(const short8*)&Bs[wn + 16 + l15][kc];
            acc[0][0] = __builtin_amdgcn_mfma_f32_16x16x32_bf16(a0s, b0s, acc[0][0], 0, 0, 0);
            acc[0][1] = __builtin_amdgcn_mfma_f32_16x16x32_bf16(a0s, b1s, acc[0][1], 0, 0, 0);
            acc[1][0] = __builtin_amdgcn_mfma_f32_16x16x32_bf16(a1s, b0s, acc[1][0], 0, 0, 0);
            acc[1][1] = __builtin_amdgcn_mfma_f32_16x16x32_bf16(a1s, b1s, acc[1][1], 0, 0, 0);
        }
    }
    // transpose via LDS (reuse As), coalesced 16B chunk stores
    ushort* sT = &As[0][0];
    int ddBase = (n0 & 255) >> 3;
    float sp[2] = {0.f, 0.f};
    __syncthreads();
    #pragma unroll
    for (int mt = 0; mt < 2; ++mt)
        #pragma unroll
        for (int nt = 0; nt < 2; ++nt) {
            int col_l = wn + nt * 16 + l15;
            #pragma unroll
            for (int i = 0; i < 4; ++i) {
                int row_l = wm + mt * 16 + lk * 4 + i;
                float v = acc[mt][nt][i];
                if (seg == 0) v *= QSCALE;
                sT[row_l * TSTRIDE + col_l] = f2bf(v);
                sp[nt] += v;
            }
        }
    __syncthreads();
    for (int c = tid; c < 512; c += 256) {
        int rl = c & 63, hh = c >> 6;
        const ushort* tp = sT + rl * TSTRIDE + hh;
        uint4 pk;
        pk.x = (unsigned)tp[0]  | ((unsigned)tp[8]  << 16);
        pk.y = (unsigned)tp[16] | ((unsigned)tp[24] << 16);
        pk.z = (unsigned)tp[32] | ((unsigned)tp[40] << 16);
        pk.w = (unsigned)tp[48] | ((unsigned)tp[56] << 16);
        int row = m0 + rl;
        if (seg == 0)
            *(uint4*)(qh + ((size_t)hh * NN + row) * HDIM + ddBase) = pk;
        else
            *(uint4*)(kvh + ((size_t)hh * NN + row) * 64 +
                      ((seg == 2) ? 32 : 0) + ddBase) = pk;
    }
    if (seg == 2) {
        int slot = ((wm >> 5) << 2) | lk;
        sRedS[slot][wn + l15]      = sp[0];
        sRedS[slot][wn + 16 + l15] = sp[1];
        __syncthreads();
        if (tid < 64) {
            float ss = 0.f;
            #pragma unroll
            for (int r = 0; r < 8; ++r) ss += sRedS[r][tid];
            int c = (n0 & 255) + tid;           // v column
            vpart[(size_t)by * 256 + (c & 7) * 32 + (c >> 3)] = ss;  // head-major
        }
    }
}

// ---------------- bf16 MFMA GEMM, XCD-swizzled -----------------------------
// aMode 0: A bf16 [M,K]. aMode 1: A fp32 + on-load BN (scale/shift from LDS,
//   computed in prologue when bnfin=1). aMode 2: A bf16 head-major.
// bMode 0: B bf16 [Nn,K]. bMode 1: B fp32 [Nn,K] converted on load.
// storeMode 0: Cf fp32 (+resid). 1: Cb bf16 (relu opt).
//   3: Cf fp32, residual recomputed as yres*scR+shR (Cf may alias yres).
// bnstat: per-block col sum/sumsq partials -> bnps/bnpq [nby][256].
// bnfin: prologue reduces bnpsIn/bnpqIn + gIn/bshIn -> LDS scale/shift,
//   and redundantly writes scOut/shOut (identical bits from every block).
__global__ __launch_bounds__(256) void gemm_bf(
    const void* __restrict__ Aptr, const void* __restrict__ Bptr,
    const float* __restrict__ resid,
    const float* yres, const float* __restrict__ scR, const float* __restrict__ shR,
    float* Cf, ushort* __restrict__ Cb,
    float* __restrict__ bnps, float* __restrict__ bnpq,
    const float* __restrict__ bnpsIn, const float* __restrict__ bnpqIn,
    const float* __restrict__ gIn, const float* __restrict__ bshIn,
    float* __restrict__ scOut, float* __restrict__ shOut,
    int M, int Nn, int K, int aMode, int bMode, int storeMode, int relu,
    int bnstat, int bnfin)
{
    __shared__ ushort As[64][LDP];
    __shared__ ushort Bs[64][LDP];
    __shared__ float sRedS[8][64];
    __shared__ float sRedQ[8][64];
    float* sSc = &sRedS[0][0];   // alias (bnfin path only; bnstat==0 then)
    float* sSh = &sRedQ[0][0];
    int tid = threadIdx.x;
    int lane = tid & 63, w = tid >> 6;
    int wm = (w >> 1) * 32, wn = (w & 1) * 32;
    int nbx = gridDim.x, nbyq = gridDim.y >> 3;
    int orig = blockIdx.y * nbx + blockIdx.x;
    int xcd = orig & 7, pos = orig >> 3;
    int by = xcd * nbyq + pos / nbx;
    int bx = pos % nbx;
    int m0 = by * 64, n0 = bx * 64;
    int l15 = lane & 15, lk = lane >> 4;
    int srow = tid >> 3;
    int scol = (tid & 7) * 8;

    if (bnfin) {
        float s = 0.f, q = 0.f;
        #pragma unroll 8
        for (int bb = 0; bb < 64; ++bb) {
            s += bnpsIn[bb * DIM + tid];
            q += bnpqIn[bb * DIM + tid];
        }
        float m = s * (1.f / NN);
        float var = q * (1.f / NN) - m * m;
        float sc = rsqrtf(var + EPS_BN) * gIn[tid];
        float sh = bshIn[tid] - m * sc;
        sSc[tid] = sc;
        sSh[tid] = sh;
        scOut[tid] = sc;     // redundant identical writes (deterministic)
        shOut[tid] = sh;
        __syncthreads();
    }

    f32x4 acc[2][2] = {};
    for (int k0 = 0; k0 < K; k0 += 64) {
        uint4 ga0, ga1, gb0, gb1;
        if (bMode == 0) {
            const ushort* Bg = (const ushort*)Bptr + (size_t)(n0 + srow) * K + scol + k0;
            gb0 = *(const uint4*)Bg;
            gb1 = *(const uint4*)(Bg + (size_t)32 * K);
        } else {
            const float* Bf = (const float*)Bptr + (size_t)(n0 + srow) * K + scol + k0;
            gb0 = pack8(*(const float4*)Bf, *(const float4*)(Bf + 4));
            gb1 = pack8(*(const float4*)(Bf + (size_t)32 * K),
                        *(const float4*)(Bf + (size_t)32 * K + 4));
        }
        if (aMode == 0) {
            const ushort* Ag = (const ushort*)Aptr + (size_t)(m0 + srow) * K + scol + k0;
            ga0 = *(const uint4*)Ag;
            ga1 = *(const uint4*)(Ag + (size_t)32 * K);
        } else if (aMode == 2) {
            int c0 = k0 + scol;
            int hh = c0 >> 5, dd = c0 & 31;
            const ushort* Ag = (const ushort*)Aptr +
                ((size_t)hh * NN + m0 + srow) * HDIM + dd;
            ga0 = *(const uint4*)Ag;
            ga1 = *(const uint4*)(Ag + (size_t)32 * HDIM);
        } else {
            const float* Af = (const float*)Aptr + (size_t)(m0 + srow) * K + scol + k0;
            float4 sc0 = *(const float4*)&sSc[k0 + scol];
            float4 sc1 = *(const float4*)&sSc[k0 + scol + 4];
            float4 sh0 = *(const float4*)&sSh[k0 + scol];
            float4 sh1 = *(const float4*)&sSh[k0 + scol + 4];
            float4 a0 = *(const float4*)Af;
            float4 a1 = *(const float4*)(Af + 4);
            float4 b0 = *(const float4*)(Af + (size_t)32 * K);
            float4 b1 = *(const float4*)(Af + (size_t)32 * K + 4);
            float4 p0, p1;
            p0.x = a0.x*sc0.x+sh0.x; p0.y = a0.y*sc0.y+sh0.y;
            p0.z = a0.z*sc0.z+sh0.z; p0.w = a0.w*sc0.w+sh0.w;
            p1.x = a1.x*sc1.x+sh1.x; p1.y = a1.y*sc1.y+sh1.y;
            p1.z = a1.z*sc1.z+sh1.z; p1.w = a1.w*sc1.w+sh1.w;
            ga0 = pack8(p0, p1);
            p0.x = b0.x*sc0.x+sh0.x; p0.y = b0.y*sc0.y+sh0.y;
            p0.z = b0.z*sc0.z+sh0.z; p0.w = b0.w*sc0.w+sh0.w;
            p1.x = b1.x*sc1.x+sh1.x; p1.y = b1.y*sc1.y+sh1.y;
            p1.z = b1.z*sc1.z+sh1.z; p1.w = b1.w*sc1.w+sh1.w;
            ga1 = pack8(p0, p1);
        }
        __syncthreads();
        *(uint4*)&As[srow][scol]      = ga0;
        *(uint4*)&As[srow + 32][scol] = ga1;
        *(uint4*)&Bs[srow][scol]      = gb0;
        *(uint4*)&Bs[srow + 32][scol] = gb1;
        __syncthreads();
        #pragma unroll
        for (int ks = 0; ks < 2; ++ks) {
            int kc = ks * 32 + lk * 8;
            short8 a0 = *(const short8*)&As[wm      + l15][kc];
            short8 a1 = *(const short8*)&As[wm + 16 + l15][kc];
            short8 b0 = *(const short8*)&Bs[wn      + l15][kc];
            short8 b1 = *(const short8*)&Bs[wn + 16 + l15][kc];
            acc[0][0] = __builtin_amdgcn_mfma_f32_16x16x32_bf16(a0, b0, acc[0][0], 0, 0, 0);
            acc[0][1] = __builtin_amdgcn_mfma_f32_16x16x32_bf16(a0, b1, acc[0][1], 0, 0, 0);
            acc[1][0] = __builtin_amdgcn_mfma_f32_16x16x32_bf16(a1, b0, acc[1][0], 0, 0, 0);
            acc[1][1] = __builtin_amdgcn_mfma_f32_16x16x32_bf16(a1, b1, acc[1][1], 0, 0, 0);
        }
    }

    float sp[2] = {0.f, 0.f}, qp[2] = {0.f, 0.f};
    #pragma unroll
    for (int mt = 0; mt < 2; ++mt) {
        #pragma unroll
        for (int nt = 0; nt < 2; ++nt) {
            int col = n0 + wn + nt * 16 + l15;
            #pragma unroll
            for (int i = 0; i < 4; ++i) {
                int row = m0 + wm + mt * 16 + lk * 4 + i;
                float v = acc[mt][nt][i];
                if (storeMode == 0) {
                    if (resid) v += resid[(size_t)row * Nn + col];
                    Cf[(size_t)row * Nn + col] = v;
                } else if (storeMode == 1) {
                    if (relu) v = fmaxf(v, 0.f);
                    Cb[(size_t)row * Nn + col] = f2bf(v);
                } else { // 3
                    v += yres[(size_t)row * Nn + col] * scR[col] + shR[col];
                    Cf[(size_t)row * Nn + col] = v;
                }
                if (bnstat) { sp[nt] += v; qp[nt] += v * v; }
            }
        }
    }
    if (bnstat) {
        int slot = ((wm >> 5) << 2) | lk;
        __syncthreads();
        sRedS[slot][wn + l15]      = sp[0];
        sRedQ[slot][wn + l15]      = qp[0];
        sRedS[slot][wn + 16 + l15] = sp[1];
        sRedQ[slot][wn + 16 + l15] = qp[1];
        __syncthreads();
        if (tid < 64) {
            float ss = 0.f, qq = 0.f;
            #pragma unroll
            for (int r = 0; r < 8; ++r) { ss += sRedS[r][tid]; qq += sRedQ[r][tid]; }
            bnps[(size_t)by * DIM + n0 + tid] = ss;
            bnpq[(size_t)by * DIM + n0 + tid] = qq;
        }
    }
}

// ---------------- BN2 finalize + apply (per-block redundant finalize) ------
__global__ __launch_bounds__(256) void bn2_fin(
    const float* __restrict__ y,
    const float* __restrict__ bnps, const float* __restrict__ bnpq,
    const float* __restrict__ g, const float* __restrict__ bsh,
    float* __restrict__ out)
{
    __shared__ float sSc[256], sSh[256];
    int tid = threadIdx.x, b = blockIdx.x;
    {
        float s = 0.f, q = 0.f;
        #pragma unroll 8
        for (int bb = 0; bb < 64; ++bb) {
            s += bnps[bb * DIM + tid];
            q += bnpq[bb * DIM + tid];
        }
        float m = s * (1.f / NN);
        float var = q * (1.f / NN) - m * m;
        float sc = rsqrtf(var + EPS_BN) * g[tid];
        sSc[tid] = sc;
        sSh[tid] = bsh[tid] - m * sc;
    }
    __syncthreads();
    int c4 = (tid & 63) * 4;
    float4 sc = *(float4*)&sSc[c4];
    float4 sh = *(float4*)&sSh[c4];
    #pragma unroll
    for (int it = 0; it < 2; ++it) {
        size_t i4 = (size_t)b * 512 + it * 256 + tid;   // float4 index
        float4 v = ((const float4*)y)[i4];
        float4 r;
        r.x = v.x * sc.x + sh.x;
        r.y = v.y * sc.y + sh.y;
        r.z = v.z * sc.z + sh.z;
        r.w = v.w * sc.w + sh.w;
        ((float4*)out)[i4] = r;
    }
}

// ---------------- head-partitioned sparse masked attention -----------------
// Blocks 0..4095: head hH = b&7 (XCD-local), rows rg*8..rg*8+7; per-block
// vsum reduce from HEAD-MAJOR vpart (coalesced 128B rows). Blocks
// 4096..4127: Wo permuted convert (consumed by the NEXT dispatch).
__global__ __launch_bounds__(256) void attn3(
    const ushort* __restrict__ qh, const ushort* __restrict__ kvh,
    const float* __restrict__ vpart,
    const unsigned* __restrict__ packed, const int* __restrict__ cnt,
    ushort* __restrict__ outh,
    const float* __restrict__ Wo, ushort* __restrict__ wo_b)
{
    __shared__ float    sQ[8][32];
    __shared__ unsigned sPk[8][CAP];
    __shared__ float    sS[8][CAP];
    __shared__ float    sRd[8];
    __shared__ float    sVred[8][32];
    __shared__ float    sVs[32];

    int tid = threadIdx.x, b = blockIdx.x;
    if (b >= 4096) {
        // Wo permuted convert: dest[row][h*32+d] = src[row][d*8+h]
        int off = b - 4096;
        int row = off * 8 + (tid >> 5), t = tid & 31;
        int hh = t >> 2, dd0 = (t & 3) * 8;
        const float* src = Wo + (size_t)row * 256 + hh;
        ushort tmp[8];
        #pragma unroll
        for (int i = 0; i < 8; ++i) tmp[i] = f2bf(src[(size_t)(dd0 + i) * 8]);
        uint4 u;
        u.x = (unsigned)tmp[0] | ((unsigned)tmp[1] << 16);
        u.y = (unsigned)tmp[2] | ((unsigned)tmp[3] << 16);
        u.z = (unsigned)tmp[4] | ((unsigned)tmp[5] << 16);
        u.w = (unsigned)tmp[6] | ((unsigned)tmp[7] << 16);
        *(uint4*)(wo_b + (size_t)row * 256 + hh * 32 + dd0) = u;
        return;
    }
    int hH = b & 7, rg = b >> 3;
    int r = tid >> 5, l = tid & 31;
    int n = rg * 8 + r;
    int nnz = cnt[n];

    sQ[r][l] = bf2f(qh[((size_t)hH * NN + n) * HDIM + l]);
    for (int j = l; j < nnz; j += 32) sPk[r][j] = packed[n * CAP + j];
    // per-block vsum: head-major vpart -> coalesced 128B rows
    {
        float vs = 0.f;
        #pragma unroll
        for (int bb = r; bb < 64; bb += 8)
            vs += vpart[(size_t)bb * 256 + hH * 32 + l];
        sVred[r][l] = vs;
    }
    __syncthreads();
    if (r == 0) {
        float t = 0.f;
        #pragma unroll
        for (int i = 0; i < 8; ++i) t += sVred[i][l];
        sVs[l] = t;
    }

    // phase 1: scores + weights + denom (32 lanes split j within the row)
    float4 qreg[8];
    #pragma unroll
    for (int t = 0; t < 8; ++t) qreg[t] = ((const float4*)sQ[r])[t];
    float lsum = 0.0f;
    for (int j = l; j < nnz; j += 32) {
        unsigned pk = sPk[r][j];
        int m = pk & 0xFFFF;
        float a = bfhi(pk);
        const uint4* kp = (const uint4*)(kvh + ((size_t)hH * NN + m) * 64);
        uint4 k0 = kp[0], k1 = kp[1], k2 = kp[2], k3 = kp[3];
        float s =
            bflo(k0.x)*qreg[0].x + bfhi(k0.x)*qreg[0].y +
            bflo(k0.y)*qreg[0].z + bfhi(k0.y)*qreg[0].w +
            bflo(k0.z)*qreg[1].x + bfhi(k0.z)*qreg[1].y +
            bflo(k0.w)*qreg[1].z + bfhi(k0.w)*qreg[1].w +
            bflo(k1.x)*qreg[2].x + bfhi(k1.x)*qreg[2].y +
            bflo(k1.y)*qreg[2].z + bfhi(k1.y)*qreg[2].w +
            bflo(k1.z)*qreg[3].x + bfhi(k1.z)*qreg[3].y +
            bflo(k1.w)*qreg[3].z + bfhi(k1.w)*qreg[3].w +
            bflo(k2.x)*qreg[4].x + bfhi(k2.x)*qreg[4].y +
            bflo(k2.y)*qreg[4].z + bfhi(k2.y)*qreg[4].w +
            bflo(k2.z)*qreg[5].x + bfhi(k2.z)*qreg[5].y +
            bflo(k2.w)*qreg[5].z + bfhi(k2.w)*qreg[5].w +
            bflo(k3.x)*qreg[6].x + bfhi(k3.x)*qreg[6].y +
            bflo(k3.y)*qreg[6].z + bfhi(k3.y)*qreg[6].w +
            bflo(k3.z)*qreg[7].x + bfhi(k3.z)*qreg[7].y +
            bflo(k3.w)*qreg[7].z + bfhi(k3.w)*qreg[7].w;
        s *= a;
        float ww = __expf(s);
        sS[r][j] = ww - 1.0f;
        lsum += ww;
    }
    #pragma unroll
    for (int o = 16; o > 0; o >>= 1) lsum += __shfl_xor(lsum, o, 32);
    if (l == 0) sRd[r] = 1.0f / (lsum + (float)(NN - nnz));
    __syncthreads();   // covers sRd and sVs

    // phase 2: lane = (jsub = l>>3, dq = l&7); 4-way j split, uint2 gathers
    int jsub = l >> 3, dq = l & 7;
    const ushort* vbase = kvh + (size_t)hH * NN * 64 + 32 + dq * 4;
    float a0 = 0.f, a1 = 0.f, a2 = 0.f, a3 = 0.f;
    for (int j = jsub; j < nnz; j += 4) {
        float ww = sS[r][j];
        int m = sPk[r][j] & 0xFFFF;
        uint2 vv = *(const uint2*)(vbase + (size_t)m * 64);
        a0 += ww * bflo(vv.x); a1 += ww * bfhi(vv.x);
        a2 += ww * bflo(vv.y); a3 += ww * bfhi(vv.y);
    }
    #pragma unroll
    for (int o = 8; o < 32; o <<= 1) {
        a0 += __shfl_xor(a0, o, 32);
        a1 += __shfl_xor(a1, o, 32);
        a2 += __shfl_xor(a2, o, 32);
        a3 += __shfl_xor(a3, o, 32);
    }
    if (jsub == 0) {
        float rd = sRd[r];
        int d0 = dq * 4;
        float r0 = (a0 + sVs[d0 + 0]) * rd;
        float r1 = (a1 + sVs[d0 + 1]) * rd;
        float r2 = (a2 + sVs[d0 + 2]) * rd;
        float r3 = (a3 + sVs[d0 + 3]) * rd;
        uint2 st;
        st.x = (unsigned)f2bf(r0) | ((unsigned)f2bf(r1) << 16);
        st.y = (unsigned)f2bf(r2) | ((unsigned)f2bf(r3) << 16);
        *(uint2*)(outh + ((size_t)hH * NN + n) * HDIM + d0) = st;
    }
}

// ---------------------------------------------------------------------------
extern "C" void kernel_launch(void* const* d_in, const int* in_sizes, int n_in,
                              void* d_out, int out_size, void* d_ws, size_t ws_size,
                              hipStream_t stream)
{
    const float* A  = (const float*)d_in[0];
    const float* h  = (const float*)d_in[1];
    const float* Wq = (const float*)d_in[2];
    const float* Wk = (const float*)d_in[3];
    const float* Wv = (const float*)d_in[4];
    const float* Wo = (const float*)d_in[5];
    const float* g1 = (const float*)d_in[6];
    const float* b1 = (const float*)d_in[7];
    const float* g2 = (const float*)d_in[8];
    const float* b2 = (const float*)d_in[9];
    const float* W1 = (const float*)d_in[10];
    const float* W2 = (const float*)d_in[11];
    float* out = (float*)d_out;
    char* w = (char*)d_ws;

    unsigned* packed = (unsigned*)(w);           // [0,2M)  nz lists
    int*    nzcnt  = (int*)(w + 2 * MB);
    ushort* wo_b   = (ushort*)(w + 5 * MB);      // 128 KB k-permuted Wo
    ushort* qh_bf  = (ushort*)(w + 6 * MB);      // 2 MB [8][4096][32]
    ushort* kvh    = (ushort*)(w + 8 * MB);      // 4 MB [8][4096][64] k|v
    ushort* ao_hb  = (ushort*)(w + 12 * MB);     // 2 MB [8][4096][32] head-major
    float*  y      = (float*)(w + 14 * MB);      // 4 MB
    ushort* t_bf   = (ushort*)(w + 18 * MB);     // 4 MB FFN hidden
    float*  vpart  = (float*)(w + 22 * MB);      // 64 KB [64][8][32] head-major
    float*  bnps   = (float*)(w + 23 * MB);
    float*  bnpq   = (float*)(w + 23 * MB + 64 * 1024);
    float*  scale1 = (float*)(w + 24 * MB);
    float*  shift1 = scale1 + 256;

    dim3 blk(256);

    // 1: fused QKV gemm (h + Wq/Wk/Wv converted on load) + A nz-scan
    qkv_ascan<<<4864, blk, 0, stream>>>(h, Wq, Wk, Wv, qh_bf, kvh, vpart,
                                        A, packed, nzcnt);
    // 2: attention (per-block vsum, head-major vpart) + Wo convert blocks
    attn3<<<4128, blk, 0, stream>>>(qh_bf, kvh, vpart, packed, nzcnt, ao_hb,
                                    Wo, wo_b);
    // 3: Wo projection + residual(h) -> y, with BN1 stat partials
    gemm_bf<<<dim3(4, 64), blk, 0, stream>>>(ao_hb, wo_b,
        h, nullptr, nullptr, nullptr,
        y, nullptr, bnps, bnpq,
        nullptr, nullptr, nullptr, nullptr, nullptr, nullptr,
        NN, DIM, DIM, 2, 0, 0, 0, 1, 0);
    // 4: FFN1 — per-block BN1 finalize + on-load BN + relu (B = fp32 W1)
    gemm_bf<<<dim3(8, 64), blk, 0, stream>>>(y, W1,
        nullptr, nullptr, nullptr, nullptr,
        nullptr, t_bf, nullptr, nullptr,
        bnps, bnpq, g1, b1, scale1, shift1,
        NN, DFF, DIM, 1, 1, 1, 1, 0, 1);
    // 5: FFN2 + recomputed BN1 residual (B = fp32 W2), BN2 partials
    gemm_bf<<<dim3(4, 64), blk, 0, stream>>>(t_bf, W2,
        nullptr, y, scale1, shift1,
        y, nullptr, bnps, bnpq,
        nullptr, nullptr, nullptr, nullptr, nullptr, nullptr,
        NN, DIM, DFF, 0, 1, 3, 0, 1, 0);
    // 6: BN2 finalize (per-block) + apply -> d_out
    bn2_fin<<<512, blk, 0, stream>>>(y, bnps, bnpq, g2, b2, out);
}

// Round 18
// 87.941 us; speedup vs baseline: 1.0579x; 1.0074x over previous
//
#include <hip/hip_runtime.h>
#include <math.h>

#define NN 4096        // nodes
#define DIM 256        // hidden
#define NHEAD 8
#define HDIM 32
#define DFF 512
#define CAP 128        // max nonzeros per row (mean ~41, max ~75 at p=.01)
#define EPS_BN 1e-5f
#define QSCALE 0.0625f // D^-0.5
#define MB (1u << 20)

typedef __attribute__((ext_vector_type(8))) short short8;
typedef __attribute__((ext_vector_type(4))) float f32x4;

__device__ inline ushort f2bf(float x) {   // RNE float->bf16
    unsigned u = __builtin_bit_cast(unsigned, x);
    unsigned r = u + 0x7FFF + ((u >> 16) & 1);
    return (ushort)(r >> 16);
}
__device__ inline float bf2f(ushort u) {
    return __builtin_bit_cast(float, (unsigned)u << 16);
}
__device__ inline float bflo(unsigned u) { return __builtin_bit_cast(float, u << 16); }
__device__ inline float bfhi(unsigned u) { return __builtin_bit_cast(float, u & 0xFFFF0000u); }
__device__ inline uint4 pack8(float4 a, float4 b) {
    uint4 u;
    u.x = (unsigned)f2bf(a.x) | ((unsigned)f2bf(a.y) << 16);
    u.y = (unsigned)f2bf(a.z) | ((unsigned)f2bf(a.w) << 16);
    u.z = (unsigned)f2bf(b.x) | ((unsigned)f2bf(b.y) << 16);
    u.w = (unsigned)f2bf(b.z) | ((unsigned)f2bf(b.w) << 16);
    return u;
}

// ---------------- fused: QKV gemm (blocks 0..767) + A nz-scan (768..4863) --
// GEMM: A = fp32 h converted on load; B = fp32 Wq/Wk/Wv (seg = n0>>8)
// converted on load (L2-resident re-reads). v col-sum partials stored
// HEAD-MAJOR: vpart[by][h*32+d] (coalesced per-head slices for attn3).
#define LDP 88
#define TSTRIDE 74
__global__ __launch_bounds__(256) void qkv_ascan(
    const float* __restrict__ hF,
    const float* __restrict__ Wq, const float* __restrict__ Wk,
    const float* __restrict__ Wv,
    ushort* __restrict__ qh, ushort* __restrict__ kvh,
    float* __restrict__ vpart,
    const float* __restrict__ Araw, unsigned* __restrict__ packed,
    int* __restrict__ cnt)
{
    __shared__ ushort As[64][LDP];
    __shared__ ushort Bs[64][LDP];
    __shared__ float sRedS[8][64];
    int b = blockIdx.x, tid = threadIdx.x;

    if (b >= 768) {
        // ---- A-scan branch ----
        int* scan = (int*)&As[0][0];
        int n = b - 768;
        const float* row = Araw + (size_t)n * NN;
        float4 vals[4];
        int c = 0;
        #pragma unroll
        for (int i = 0; i < 4; ++i) {
            vals[i] = *(const float4*)(row + i * 1024 + tid * 4);
            c += (vals[i].x != 0.f) + (vals[i].y != 0.f)
               + (vals[i].z != 0.f) + (vals[i].w != 0.f);
        }
        scan[tid] = c;
        __syncthreads();
        for (int off = 1; off < 256; off <<= 1) {
            int t = (tid >= off) ? scan[tid - off] : 0;
            __syncthreads();
            scan[tid] += t;
            __syncthreads();
        }
        int pos = scan[tid] - c;       // exclusive prefix
        int total = scan[255];
        #pragma unroll
        for (int i = 0; i < 4; ++i) {
            int cb = i * 1024 + tid * 4;
            float4 v = vals[i];
            if (v.x != 0.f && pos < CAP) { packed[n*CAP+pos] = ((unsigned)f2bf(v.x) << 16) | (unsigned)cb;       ++pos; }
            if (v.y != 0.f && pos < CAP) { packed[n*CAP+pos] = ((unsigned)f2bf(v.y) << 16) | (unsigned)(cb + 1); ++pos; }
            if (v.z != 0.f && pos < CAP) { packed[n*CAP+pos] = ((unsigned)f2bf(v.z) << 16) | (unsigned)(cb + 2); ++pos; }
            if (v.w != 0.f && pos < CAP) { packed[n*CAP+pos] = ((unsigned)f2bf(v.w) << 16) | (unsigned)(cb + 3); ++pos; }
        }
        if (tid == 0) cnt[n] = min(total, CAP);
        return;
    }

    // ---- QKV GEMM branch ----
    int lane = tid & 63, w = tid >> 6;
    int wm = (w >> 1) * 32, wn = (w & 1) * 32;
    int xcd = b & 7, pos = b >> 3;
    int by = xcd * 8 + pos / 12;
    int bx = pos % 12;
    int m0 = by * 64, n0 = bx * 64;
    int seg = n0 >> 8;                  // 0:q 1:k 2:v (64-row panel in one seg)
    const float* Wsrc = (seg == 0) ? Wq : ((seg == 1) ? Wk : Wv);
    int l15 = lane & 15, lk = lane >> 4;
    int srow = tid >> 3;
    int scol = (tid & 7) * 8;

    f32x4 acc[2][2] = {};
    for (int k0 = 0; k0 < DIM; k0 += 64) {
        const float* Bf = Wsrc + (size_t)((n0 & 255) + srow) * DIM + scol + k0;
        uint4 gb0 = pack8(*(const float4*)Bf, *(const float4*)(Bf + 4));
        uint4 gb1 = pack8(*(const float4*)(Bf + (size_t)32 * DIM),
                          *(const float4*)(Bf + (size_t)32 * DIM + 4));
        const float* Af = hF + (size_t)(m0 + srow) * DIM + scol + k0;
        uint4 ga0 = pack8(*(const float4*)Af, *(const float4*)(Af + 4));
        uint4 ga1 = pack8(*(const float4*)(Af + (size_t)32 * DIM),
                          *(const float4*)(Af + (size_t)32 * DIM + 4));
        __syncthreads();
        *(uint4*)&As[srow][scol]      = ga0;
        *(uint4*)&As[srow + 32][scol] = ga1;
        *(uint4*)&Bs[srow][scol]      = gb0;
        *(uint4*)&Bs[srow + 32][scol] = gb1;
        __syncthreads();
        #pragma unroll
        for (int ks = 0; ks < 2; ++ks) {
            int kc = ks * 32 + lk * 8;
            short8 a0s = *(const short8*)&As[wm      + l15][kc];
            short8 a1s = *(const short8*)&As[wm + 16 + l15][kc];
            short8 b0s = *(const short8*)&Bs[wn      + l15][kc];
            short8 b1s = *(const short8*)&Bs[wn + 16 + l15][kc];
            acc[0][0] = __builtin_amdgcn_mfma_f32_16x16x32_bf16(a0s, b0s, acc[0][0], 0, 0, 0);
            acc[0][1] = __builtin_amdgcn_mfma_f32_16x16x32_bf16(a0s, b1s, acc[0][1], 0, 0, 0);
            acc[1][0] = __builtin_amdgcn_mfma_f32_16x16x32_bf16(a1s, b0s, acc[1][0], 0, 0, 0);
            acc[1][1] = __builtin_amdgcn_mfma_f32_16x16x32_bf16(a1s, b1s, acc[1][1], 0, 0, 0);
        }
    }
    // transpose via LDS (reuse As), coalesced 16B chunk stores
    ushort* sT = &As[0][0];
    int ddBase = (n0 & 255) >> 3;
    float sp[2] = {0.f, 0.f};
    __syncthreads();
    #pragma unroll
    for (int mt = 0; mt < 2; ++mt)
        #pragma unroll
        for (int nt = 0; nt < 2; ++nt) {
            int col_l = wn + nt * 16 + l15;
            #pragma unroll
            for (int i = 0; i < 4; ++i) {
                int row_l = wm + mt * 16 + lk * 4 + i;
                float v = acc[mt][nt][i];
                if (seg == 0) v *= QSCALE;
                sT[row_l * TSTRIDE + col_l] = f2bf(v);
                sp[nt] += v;
            }
        }
    __syncthreads();
    for (int c = tid; c < 512; c += 256) {
        int rl = c & 63, hh = c >> 6;
        const ushort* tp = sT + rl * TSTRIDE + hh;
        uint4 pk;
        pk.x = (unsigned)tp[0]  | ((unsigned)tp[8]  << 16);
        pk.y = (unsigned)tp[16] | ((unsigned)tp[24] << 16);
        pk.z = (unsigned)tp[32] | ((unsigned)tp[40] << 16);
        pk.w = (unsigned)tp[48] | ((unsigned)tp[56] << 16);
        int row = m0 + rl;
        if (seg == 0)
            *(uint4*)(qh + ((size_t)hh * NN + row) * HDIM + ddBase) = pk;
        else
            *(uint4*)(kvh + ((size_t)hh * NN + row) * 64 +
                      ((seg == 2) ? 32 : 0) + ddBase) = pk;
    }
    if (seg == 2) {
        int slot = ((wm >> 5) << 2) | lk;
        sRedS[slot][wn + l15]      = sp[0];
        sRedS[slot][wn + 16 + l15] = sp[1];
        __syncthreads();
        if (tid < 64) {
            float ss = 0.f;
            #pragma unroll
            for (int r = 0; r < 8; ++r) ss += sRedS[r][tid];
            int c = (n0 & 255) + tid;           // v column
            vpart[(size_t)by * 256 + (c & 7) * 32 + (c >> 3)] = ss;  // head-major
        }
    }
}

// ---------------- bf16 MFMA GEMM, XCD-swizzled -----------------------------
// aMode 0: A bf16 [M,K]. aMode 1: A fp32 + on-load BN (scale/shift from LDS,
//   computed in prologue when bnfin=1). aMode 2: A bf16 head-major.
// bMode 0: B bf16 [Nn,K]. bMode 1: B fp32 [Nn,K] converted on load.
// storeMode 0: Cf fp32 (+resid). 1: Cb bf16 (relu opt).
//   3: Cf fp32, residual recomputed as yres*scR+shR (Cf may alias yres).
// bnstat: per-block col sum/sumsq partials -> bnps/bnpq [nby][256].
// bnfin: prologue reduces bnpsIn/bnpqIn + gIn/bshIn -> LDS scale/shift,
//   and redundantly writes scOut/shOut (identical bits from every block).
__global__ __launch_bounds__(256) void gemm_bf(
    const void* __restrict__ Aptr, const void* __restrict__ Bptr,
    const float* __restrict__ resid,
    const float* yres, const float* __restrict__ scR, const float* __restrict__ shR,
    float* Cf, ushort* __restrict__ Cb,
    float* __restrict__ bnps, float* __restrict__ bnpq,
    const float* __restrict__ bnpsIn, const float* __restrict__ bnpqIn,
    const float* __restrict__ gIn, const float* __restrict__ bshIn,
    float* __restrict__ scOut, float* __restrict__ shOut,
    int M, int Nn, int K, int aMode, int bMode, int storeMode, int relu,
    int bnstat, int bnfin)
{
    __shared__ ushort As[64][LDP];
    __shared__ ushort Bs[64][LDP];
    __shared__ float sRedS[8][64];
    __shared__ float sRedQ[8][64];
    float* sSc = &sRedS[0][0];   // alias (bnfin path only; bnstat==0 then)
    float* sSh = &sRedQ[0][0];
    int tid = threadIdx.x;
    int lane = tid & 63, w = tid >> 6;
    int wm = (w >> 1) * 32, wn = (w & 1) * 32;
    int nbx = gridDim.x, nbyq = gridDim.y >> 3;
    int orig = blockIdx.y * nbx + blockIdx.x;
    int xcd = orig & 7, pos = orig >> 3;
    int by = xcd * nbyq + pos / nbx;
    int bx = pos % nbx;
    int m0 = by * 64, n0 = bx * 64;
    int l15 = lane & 15, lk = lane >> 4;
    int srow = tid >> 3;
    int scol = (tid & 7) * 8;

    if (bnfin) {
        float s = 0.f, q = 0.f;
        #pragma unroll 8
        for (int bb = 0; bb < 64; ++bb) {
            s += bnpsIn[bb * DIM + tid];
            q += bnpqIn[bb * DIM + tid];
        }
        float m = s * (1.f / NN);
        float var = q * (1.f / NN) - m * m;
        float sc = rsqrtf(var + EPS_BN) * gIn[tid];
        float sh = bshIn[tid] - m * sc;
        sSc[tid] = sc;
        sSh[tid] = sh;
        scOut[tid] = sc;     // redundant identical writes (deterministic)
        shOut[tid] = sh;
        __syncthreads();
    }

    f32x4 acc[2][2] = {};
    for (int k0 = 0; k0 < K; k0 += 64) {
        uint4 ga0, ga1, gb0, gb1;
        if (bMode == 0) {
            const ushort* Bg = (const ushort*)Bptr + (size_t)(n0 + srow) * K + scol + k0;
            gb0 = *(const uint4*)Bg;
            gb1 = *(const uint4*)(Bg + (size_t)32 * K);
        } else {
            const float* Bf = (const float*)Bptr + (size_t)(n0 + srow) * K + scol + k0;
            gb0 = pack8(*(const float4*)Bf, *(const float4*)(Bf + 4));
            gb1 = pack8(*(const float4*)(Bf + (size_t)32 * K),
                        *(const float4*)(Bf + (size_t)32 * K + 4));
        }
        if (aMode == 0) {
            const ushort* Ag = (const ushort*)Aptr + (size_t)(m0 + srow) * K + scol + k0;
            ga0 = *(const uint4*)Ag;
            ga1 = *(const uint4*)(Ag + (size_t)32 * K);
        } else if (aMode == 2) {
            int c0 = k0 + scol;
            int hh = c0 >> 5, dd = c0 & 31;
            const ushort* Ag = (const ushort*)Aptr +
                ((size_t)hh * NN + m0 + srow) * HDIM + dd;
            ga0 = *(const uint4*)Ag;
            ga1 = *(const uint4*)(Ag + (size_t)32 * HDIM);
        } else {
            const float* Af = (const float*)Aptr + (size_t)(m0 + srow) * K + scol + k0;
            float4 sc0 = *(const float4*)&sSc[k0 + scol];
            float4 sc1 = *(const float4*)&sSc[k0 + scol + 4];
            float4 sh0 = *(const float4*)&sSh[k0 + scol];
            float4 sh1 = *(const float4*)&sSh[k0 + scol + 4];
            float4 a0 = *(const float4*)Af;
            float4 a1 = *(const float4*)(Af + 4);
            float4 b0 = *(const float4*)(Af + (size_t)32 * K);
            float4 b1 = *(const float4*)(Af + (size_t)32 * K + 4);
            float4 p0, p1;
            p0.x = a0.x*sc0.x+sh0.x; p0.y = a0.y*sc0.y+sh0.y;
            p0.z = a0.z*sc0.z+sh0.z; p0.w = a0.w*sc0.w+sh0.w;
            p1.x = a1.x*sc1.x+sh1.x; p1.y = a1.y*sc1.y+sh1.y;
            p1.z = a1.z*sc1.z+sh1.z; p1.w = a1.w*sc1.w+sh1.w;
            ga0 = pack8(p0, p1);
            p0.x = b0.x*sc0.x+sh0.x; p0.y = b0.y*sc0.y+sh0.y;
            p0.z = b0.z*sc0.z+sh0.z; p0.w = b0.w*sc0.w+sh0.w;
            p1.x = b1.x*sc1.x+sh1.x; p1.y = b1.y*sc1.y+sh1.y;
            p1.z = b1.z*sc1.z+sh1.z; p1.w = b1.w*sc1.w+sh1.w;
            ga1 = pack8(p0, p1);
        }
        __syncthreads();
        *(uint4*)&As[srow][scol]      = ga0;
        *(uint4*)&As[srow + 32][scol] = ga1;
        *(uint4*)&Bs[srow][scol]      = gb0;
        *(uint4*)&Bs[srow + 32][scol] = gb1;
        __syncthreads();
        #pragma unroll
        for (int ks = 0; ks < 2; ++ks) {
            int kc = ks * 32 + lk * 8;
            short8 a0 = *(const short8*)&As[wm      + l15][kc];
            short8 a1 = *(const short8*)&As[wm + 16 + l15][kc];
            short8 b0 = *(const short8*)&Bs[wn      + l15][kc];
            short8 b1 = *(const short8*)&Bs[wn + 16 + l15][kc];
            acc[0][0] = __builtin_amdgcn_mfma_f32_16x16x32_bf16(a0, b0, acc[0][0], 0, 0, 0);
            acc[0][1] = __builtin_amdgcn_mfma_f32_16x16x32_bf16(a0, b1, acc[0][1], 0, 0, 0);
            acc[1][0] = __builtin_amdgcn_mfma_f32_16x16x32_bf16(a1, b0, acc[1][0], 0, 0, 0);
            acc[1][1] = __builtin_amdgcn_mfma_f32_16x16x32_bf16(a1, b1, acc[1][1], 0, 0, 0);
        }
    }

    float sp[2] = {0.f, 0.f}, qp[2] = {0.f, 0.f};
    #pragma unroll
    for (int mt = 0; mt < 2; ++mt) {
        #pragma unroll
        for (int nt = 0; nt < 2; ++nt) {
            int col = n0 + wn + nt * 16 + l15;
            #pragma unroll
            for (int i = 0; i < 4; ++i) {
                int row = m0 + wm + mt * 16 + lk * 4 + i;
                float v = acc[mt][nt][i];
                if (storeMode == 0) {
                    if (resid) v += resid[(size_t)row * Nn + col];
                    Cf[(size_t)row * Nn + col] = v;
                } else if (storeMode == 1) {
                    if (relu) v = fmaxf(v, 0.f);
                    Cb[(size_t)row * Nn + col] = f2bf(v);
                } else { // 3
                    v += yres[(size_t)row * Nn + col] * scR[col] + shR[col];
                    Cf[(size_t)row * Nn + col] = v;
                }
                if (bnstat) { sp[nt] += v; qp[nt] += v * v; }
            }
        }
    }
    if (bnstat) {
        int slot = ((wm >> 5) << 2) | lk;
        __syncthreads();
        sRedS[slot][wn + l15]      = sp[0];
        sRedQ[slot][wn + l15]      = qp[0];
        sRedS[slot][wn + 16 + l15] = sp[1];
        sRedQ[slot][wn + 16 + l15] = qp[1];
        __syncthreads();
        if (tid < 64) {
            float ss = 0.f, qq = 0.f;
            #pragma unroll
            for (int r = 0; r < 8; ++r) { ss += sRedS[r][tid]; qq += sRedQ[r][tid]; }
            bnps[(size_t)by * DIM + n0 + tid] = ss;
            bnpq[(size_t)by * DIM + n0 + tid] = qq;
        }
    }
}

// ---------------- BN2 finalize + apply (per-block redundant finalize) ------
__global__ __launch_bounds__(256) void bn2_fin(
    const float* __restrict__ y,
    const float* __restrict__ bnps, const float* __restrict__ bnpq,
    const float* __restrict__ g, const float* __restrict__ bsh,
    float* __restrict__ out)
{
    __shared__ float sSc[256], sSh[256];
    int tid = threadIdx.x, b = blockIdx.x;
    {
        float s = 0.f, q = 0.f;
        #pragma unroll 8
        for (int bb = 0; bb < 64; ++bb) {
            s += bnps[bb * DIM + tid];
            q += bnpq[bb * DIM + tid];
        }
        float m = s * (1.f / NN);
        float var = q * (1.f / NN) - m * m;
        float sc = rsqrtf(var + EPS_BN) * g[tid];
        sSc[tid] = sc;
        sSh[tid] = bsh[tid] - m * sc;
    }
    __syncthreads();
    int c4 = (tid & 63) * 4;
    float4 sc = *(float4*)&sSc[c4];
    float4 sh = *(float4*)&sSh[c4];
    #pragma unroll
    for (int it = 0; it < 2; ++it) {
        size_t i4 = (size_t)b * 512 + it * 256 + tid;   // float4 index
        float4 v = ((const float4*)y)[i4];
        float4 r;
        r.x = v.x * sc.x + sh.x;
        r.y = v.y * sc.y + sh.y;
        r.z = v.z * sc.z + sh.z;
        r.w = v.w * sc.w + sh.w;
        ((float4*)out)[i4] = r;
    }
}

// ---------------- head-partitioned sparse masked attention -----------------
// Blocks 0..4095: head hH = b&7 (XCD-local), rows rg*8..rg*8+7; per-block
// vsum reduce from HEAD-MAJOR vpart (coalesced 128B rows). Blocks
// 4096..4127: Wo permuted convert (consumed by the NEXT dispatch).
// Phase 2: 4-way j split + 2-way unroll (two independent gathers in flight).
__global__ __launch_bounds__(256) void attn3(
    const ushort* __restrict__ qh, const ushort* __restrict__ kvh,
    const float* __restrict__ vpart,
    const unsigned* __restrict__ packed, const int* __restrict__ cnt,
    ushort* __restrict__ outh,
    const float* __restrict__ Wo, ushort* __restrict__ wo_b)
{
    __shared__ float    sQ[8][32];
    __shared__ unsigned sPk[8][CAP];
    __shared__ float    sS[8][CAP];
    __shared__ float    sRd[8];
    __shared__ float    sVred[8][32];
    __shared__ float    sVs[32];

    int tid = threadIdx.x, b = blockIdx.x;
    if (b >= 4096) {
        // Wo permuted convert: dest[row][h*32+d] = src[row][d*8+h]
        int off = b - 4096;
        int row = off * 8 + (tid >> 5), t = tid & 31;
        int hh = t >> 2, dd0 = (t & 3) * 8;
        const float* src = Wo + (size_t)row * 256 + hh;
        ushort tmp[8];
        #pragma unroll
        for (int i = 0; i < 8; ++i) tmp[i] = f2bf(src[(size_t)(dd0 + i) * 8]);
        uint4 u;
        u.x = (unsigned)tmp[0] | ((unsigned)tmp[1] << 16);
        u.y = (unsigned)tmp[2] | ((unsigned)tmp[3] << 16);
        u.z = (unsigned)tmp[4] | ((unsigned)tmp[5] << 16);
        u.w = (unsigned)tmp[6] | ((unsigned)tmp[7] << 16);
        *(uint4*)(wo_b + (size_t)row * 256 + hh * 32 + dd0) = u;
        return;
    }
    int hH = b & 7, rg = b >> 3;
    int r = tid >> 5, l = tid & 31;
    int n = rg * 8 + r;
    int nnz = cnt[n];

    sQ[r][l] = bf2f(qh[((size_t)hH * NN + n) * HDIM + l]);
    for (int j = l; j < nnz; j += 32) sPk[r][j] = packed[n * CAP + j];
    // per-block vsum: head-major vpart -> coalesced 128B rows
    {
        float vs = 0.f;
        #pragma unroll
        for (int bb = r; bb < 64; bb += 8)
            vs += vpart[(size_t)bb * 256 + hH * 32 + l];
        sVred[r][l] = vs;
    }
    __syncthreads();
    if (r == 0) {
        float t = 0.f;
        #pragma unroll
        for (int i = 0; i < 8; ++i) t += sVred[i][l];
        sVs[l] = t;
    }

    // phase 1: scores + weights + denom (32 lanes split j within the row)
    float4 qreg[8];
    #pragma unroll
    for (int t = 0; t < 8; ++t) qreg[t] = ((const float4*)sQ[r])[t];
    float lsum = 0.0f;
    for (int j = l; j < nnz; j += 32) {
        unsigned pk = sPk[r][j];
        int m = pk & 0xFFFF;
        float a = bfhi(pk);
        const uint4* kp = (const uint4*)(kvh + ((size_t)hH * NN + m) * 64);
        uint4 k0 = kp[0], k1 = kp[1], k2 = kp[2], k3 = kp[3];
        float s =
            bflo(k0.x)*qreg[0].x + bfhi(k0.x)*qreg[0].y +
            bflo(k0.y)*qreg[0].z + bfhi(k0.y)*qreg[0].w +
            bflo(k0.z)*qreg[1].x + bfhi(k0.z)*qreg[1].y +
            bflo(k0.w)*qreg[1].z + bfhi(k0.w)*qreg[1].w +
            bflo(k1.x)*qreg[2].x + bfhi(k1.x)*qreg[2].y +
            bflo(k1.y)*qreg[2].z + bfhi(k1.y)*qreg[2].w +
            bflo(k1.z)*qreg[3].x + bfhi(k1.z)*qreg[3].y +
            bflo(k1.w)*qreg[3].z + bfhi(k1.w)*qreg[3].w +
            bflo(k2.x)*qreg[4].x + bfhi(k2.x)*qreg[4].y +
            bflo(k2.y)*qreg[4].z + bfhi(k2.y)*qreg[4].w +
            bflo(k2.z)*qreg[5].x + bfhi(k2.z)*qreg[5].y +
            bflo(k2.w)*qreg[5].z + bfhi(k2.w)*qreg[5].w +
            bflo(k3.x)*qreg[6].x + bfhi(k3.x)*qreg[6].y +
            bflo(k3.y)*qreg[6].z + bfhi(k3.y)*qreg[6].w +
            bflo(k3.z)*qreg[7].x + bfhi(k3.z)*qreg[7].y +
            bflo(k3.w)*qreg[7].z + bfhi(k3.w)*qreg[7].w;
        s *= a;
        float ww = __expf(s);
        sS[r][j] = ww - 1.0f;
        lsum += ww;
    }
    #pragma unroll
    for (int o = 16; o > 0; o >>= 1) lsum += __shfl_xor(lsum, o, 32);
    if (l == 0) sRd[r] = 1.0f / (lsum + (float)(NN - nnz));
    __syncthreads();   // covers sRd and sVs

    // phase 2: lane = (jsub = l>>3, dq = l&7); 4-way j split, 2-way unroll
    int jsub = l >> 3, dq = l & 7;
    const ushort* vbase = kvh + (size_t)hH * NN * 64 + 32 + dq * 4;
    float a0 = 0.f, a1 = 0.f, a2 = 0.f, a3 = 0.f;
    int j = jsub;
    for (; j + 4 < nnz; j += 8) {
        float w1 = sS[r][j];
        float w2 = sS[r][j + 4];
        int m1 = sPk[r][j] & 0xFFFF;
        int m2 = sPk[r][j + 4] & 0xFFFF;
        uint2 v1 = *(const uint2*)(vbase + (size_t)m1 * 64);
        uint2 v2 = *(const uint2*)(vbase + (size_t)m2 * 64);
        a0 += w1 * bflo(v1.x) + w2 * bflo(v2.x);
        a1 += w1 * bfhi(v1.x) + w2 * bfhi(v2.x);
        a2 += w1 * bflo(v1.y) + w2 * bflo(v2.y);
        a3 += w1 * bfhi(v1.y) + w2 * bfhi(v2.y);
    }
    if (j < nnz) {
        float w1 = sS[r][j];
        int m1 = sPk[r][j] & 0xFFFF;
        uint2 v1 = *(const uint2*)(vbase + (size_t)m1 * 64);
        a0 += w1 * bflo(v1.x);
        a1 += w1 * bfhi(v1.x);
        a2 += w1 * bflo(v1.y);
        a3 += w1 * bfhi(v1.y);
    }
    #pragma unroll
    for (int o = 8; o < 32; o <<= 1) {
        a0 += __shfl_xor(a0, o, 32);
        a1 += __shfl_xor(a1, o, 32);
        a2 += __shfl_xor(a2, o, 32);
        a3 += __shfl_xor(a3, o, 32);
    }
    if (jsub == 0) {
        float rd = sRd[r];
        int d0 = dq * 4;
        float r0 = (a0 + sVs[d0 + 0]) * rd;
        float r1 = (a1 + sVs[d0 + 1]) * rd;
        float r2 = (a2 + sVs[d0 + 2]) * rd;
        float r3 = (a3 + sVs[d0 + 3]) * rd;
        uint2 st;
        st.x = (unsigned)f2bf(r0) | ((unsigned)f2bf(r1) << 16);
        st.y = (unsigned)f2bf(r2) | ((unsigned)f2bf(r3) << 16);
        *(uint2*)(outh + ((size_t)hH * NN + n) * HDIM + d0) = st;
    }
}

// ---------------------------------------------------------------------------
extern "C" void kernel_launch(void* const* d_in, const int* in_sizes, int n_in,
                              void* d_out, int out_size, void* d_ws, size_t ws_size,
                              hipStream_t stream)
{
    const float* A  = (const float*)d_in[0];
    const float* h  = (const float*)d_in[1];
    const float* Wq = (const float*)d_in[2];
    const float* Wk = (const float*)d_in[3];
    const float* Wv = (const float*)d_in[4];
    const float* Wo = (const float*)d_in[5];
    const float* g1 = (const float*)d_in[6];
    const float* b1 = (const float*)d_in[7];
    const float* g2 = (const float*)d_in[8];
    const float* b2 = (const float*)d_in[9];
    const float* W1 = (const float*)d_in[10];
    const float* W2 = (const float*)d_in[11];
    float* out = (float*)d_out;
    char* w = (char*)d_ws;

    unsigned* packed = (unsigned*)(w);           // [0,2M)  nz lists
    int*    nzcnt  = (int*)(w + 2 * MB);
    ushort* wo_b   = (ushort*)(w + 5 * MB);      // 128 KB k-permuted Wo
    ushort* qh_bf  = (ushort*)(w + 6 * MB);      // 2 MB [8][4096][32]
    ushort* kvh    = (ushort*)(w + 8 * MB);      // 4 MB [8][4096][64] k|v
    ushort* ao_hb  = (ushort*)(w + 12 * MB);     // 2 MB [8][4096][32] head-major
    float*  y      = (float*)(w + 14 * MB);      // 4 MB
    ushort* t_bf   = (ushort*)(w + 18 * MB);     // 4 MB FFN hidden
    float*  vpart  = (float*)(w + 22 * MB);      // 64 KB [64][8][32] head-major
    float*  bnps   = (float*)(w + 23 * MB);
    float*  bnpq   = (float*)(w + 23 * MB + 64 * 1024);
    float*  scale1 = (float*)(w + 24 * MB);
    float*  shift1 = scale1 + 256;

    dim3 blk(256);

    // 1: fused QKV gemm (h + Wq/Wk/Wv converted on load) + A nz-scan
    qkv_ascan<<<4864, blk, 0, stream>>>(h, Wq, Wk, Wv, qh_bf, kvh, vpart,
                                        A, packed, nzcnt);
    // 2: attention (per-block vsum, head-major vpart) + Wo convert blocks
    attn3<<<4128, blk, 0, stream>>>(qh_bf, kvh, vpart, packed, nzcnt, ao_hb,
                                    Wo, wo_b);
    // 3: Wo projection + residual(h) -> y, with BN1 stat partials
    gemm_bf<<<dim3(4, 64), blk, 0, stream>>>(ao_hb, wo_b,
        h, nullptr, nullptr, nullptr,
        y, nullptr, bnps, bnpq,
        nullptr, nullptr, nullptr, nullptr, nullptr, nullptr,
        NN, DIM, DIM, 2, 0, 0, 0, 1, 0);
    // 4: FFN1 — per-block BN1 finalize + on-load BN + relu (B = fp32 W1)
    gemm_bf<<<dim3(8, 64), blk, 0, stream>>>(y, W1,
        nullptr, nullptr, nullptr, nullptr,
        nullptr, t_bf, nullptr, nullptr,
        bnps, bnpq, g1, b1, scale1, shift1,
        NN, DFF, DIM, 1, 1, 1, 1, 0, 1);
    // 5: FFN2 + recomputed BN1 residual (B = fp32 W2), BN2 partials
    gemm_bf<<<dim3(4, 64), blk, 0, stream>>>(t_bf, W2,
        nullptr, y, scale1, shift1,
        y, nullptr, bnps, bnpq,
        nullptr, nullptr, nullptr, nullptr, nullptr, nullptr,
        NN, DIM, DFF, 0, 1, 3, 0, 1, 0);
    // 6: BN2 finalize (per-block) + apply -> d_out
    bn2_fin<<<512, blk, 0, stream>>>(y, bnps, bnpq, g2, b2, out);
}